// Round 4
// baseline (294.675 us; speedup 1.0000x reference)
//
#include <hip/hip_runtime.h>

#define N_TOK 131072
#define K_CODES 512
#define DIM 64

// ---- numpy pairwise_sum for n=64 (array version, used by vq_prep only) ----
__device__ __forceinline__ float np_sumsq64(const float* v) {
    float r[8];
#pragma unroll
    for (int j = 0; j < 8; ++j) r[j] = __fmul_rn(v[j], v[j]);
#pragma unroll
    for (int i = 8; i < 64; i += 8) {
#pragma unroll
        for (int j = 0; j < 8; ++j)
            r[j] = __fadd_rn(r[j], __fmul_rn(v[i + j], v[i + j]));
    }
    return __fadd_rn(__fadd_rn(__fadd_rn(r[0], r[1]), __fadd_rn(r[2], r[3])),
                     __fadd_rn(__fadd_rn(r[4], r[5]), __fadd_rn(r[6], r[7])));
}

__global__ __launch_bounds__(256) void vq_prep(const float* __restrict__ cb,
                                               float* __restrict__ cnorm) {
    int k = blockIdx.x * 256 + threadIdx.x;
    if (k < K_CODES) {
        float v[DIM];
#pragma unroll
        for (int d = 0; d < DIM; ++d) v[d] = cb[k * DIM + d];
        cnorm[k] = np_sumsq64(v);
    }
}

// macro utilities ------------------------------------------------------------
#define REP64(M) \
  M(0)  M(1)  M(2)  M(3)  M(4)  M(5)  M(6)  M(7)  \
  M(8)  M(9)  M(10) M(11) M(12) M(13) M(14) M(15) \
  M(16) M(17) M(18) M(19) M(20) M(21) M(22) M(23) \
  M(24) M(25) M(26) M(27) M(28) M(29) M(30) M(31) \
  M(32) M(33) M(34) M(35) M(36) M(37) M(38) M(39) \
  M(40) M(41) M(42) M(43) M(44) M(45) M(46) M(47) \
  M(48) M(49) M(50) M(51) M(52) M(53) M(54) M(55) \
  M(56) M(57) M(58) M(59) M(60) M(61) M(62) M(63)

// x stays in 64 NAMED scalars -> cannot be demoted to scratch (R2/R3: xr[64]
// array stayed an alloca: VGPR_Count=56, ~64MB scratch WRITE, 291us).
__global__ __attribute__((amdgpu_flat_work_group_size(256, 256),
                          amdgpu_waves_per_eu(2, 2)))
void vq_main(const float* __restrict__ x, const float* __restrict__ cb,
             const float* __restrict__ cnorm, float* __restrict__ out,
             double* __restrict__ loss_acc)
{
    const int t = blockIdx.x * 256 + threadIdx.x;

    const float4* xv = (const float4*)(x + (size_t)t * DIM);
    float4 v0 = xv[0],  v1 = xv[1],  v2 = xv[2],  v3 = xv[3],
           v4 = xv[4],  v5 = xv[5],  v6 = xv[6],  v7 = xv[7],
           v8 = xv[8],  v9 = xv[9],  v10 = xv[10], v11 = xv[11],
           v12 = xv[12], v13 = xv[13], v14 = xv[14], v15 = xv[15];
#define XQ(i, a, b, c, d) \
    float x##a = v##i.x, x##b = v##i.y, x##c = v##i.z, x##d = v##i.w;
    XQ(0, 0, 1, 2, 3)    XQ(1, 4, 5, 6, 7)    XQ(2, 8, 9, 10, 11)
    XQ(3, 12, 13, 14, 15) XQ(4, 16, 17, 18, 19) XQ(5, 20, 21, 22, 23)
    XQ(6, 24, 25, 26, 27) XQ(7, 28, 29, 30, 31) XQ(8, 32, 33, 34, 35)
    XQ(9, 36, 37, 38, 39) XQ(10, 40, 41, 42, 43) XQ(11, 44, 45, 46, 47)
    XQ(12, 48, 49, 50, 51) XQ(13, 52, 53, 54, 55) XQ(14, 56, 57, 58, 59)
    XQ(15, 60, 61, 62, 63)

    // x2: numpy pairwise_sum order, terms fl(x*x), strict IEEE (no contract)
    float r0 = __fmul_rn(x0, x0), r1 = __fmul_rn(x1, x1),
          r2 = __fmul_rn(x2, x2), r3 = __fmul_rn(x3, x3),
          r4 = __fmul_rn(x4, x4), r5 = __fmul_rn(x5, x5),
          r6 = __fmul_rn(x6, x6), r7 = __fmul_rn(x7, x7);
#define SQROW(a, b, c, d, e, f, g, h) \
    r0 = __fadd_rn(r0, __fmul_rn(x##a, x##a)); \
    r1 = __fadd_rn(r1, __fmul_rn(x##b, x##b)); \
    r2 = __fadd_rn(r2, __fmul_rn(x##c, x##c)); \
    r3 = __fadd_rn(r3, __fmul_rn(x##d, x##d)); \
    r4 = __fadd_rn(r4, __fmul_rn(x##e, x##e)); \
    r5 = __fadd_rn(r5, __fmul_rn(x##f, x##f)); \
    r6 = __fadd_rn(r6, __fmul_rn(x##g, x##g)); \
    r7 = __fadd_rn(r7, __fmul_rn(x##h, x##h));
    SQROW(8, 9, 10, 11, 12, 13, 14, 15)
    SQROW(16, 17, 18, 19, 20, 21, 22, 23)
    SQROW(24, 25, 26, 27, 28, 29, 30, 31)
    SQROW(32, 33, 34, 35, 36, 37, 38, 39)
    SQROW(40, 41, 42, 43, 44, 45, 46, 47)
    SQROW(48, 49, 50, 51, 52, 53, 54, 55)
    SQROW(56, 57, 58, 59, 60, 61, 62, 63)
    const float x2s =
        __fadd_rn(__fadd_rn(__fadd_rn(r0, r1), __fadd_rn(r2, r3)),
                  __fadd_rn(__fadd_rn(r4, r5), __fadd_rn(r6, r7)));

    // screen all K codes, 4 independent serial FMA chains (d ascending ==
    // BLAS sgemm microkernel order; matched bit-exact in R2/R3, absmax 0.0)
    float best = __int_as_float(0x7f800000);  // +inf
    int bidx = 0;
    for (int kg = 0; kg < K_CODES; kg += 4) {
        const int kk = __builtin_amdgcn_readfirstlane(kg);  // SGPR/s_load path
        const float* cA = cb + ((size_t)kk << 6);
        const float* cB = cA + 64;
        const float* cC = cA + 128;
        const float* cD = cA + 192;
        float a0 = 0.f, a1 = 0.f, a2 = 0.f, a3 = 0.f;
#define FMA_D(d) \
        a0 = __fmaf_rn(x##d, cA[d], a0); \
        a1 = __fmaf_rn(x##d, cB[d], a1); \
        a2 = __fmaf_rn(x##d, cC[d], a2); \
        a3 = __fmaf_rn(x##d, cD[d], a3);
        REP64(FMA_D)
#undef FMA_D
        float d2_0 = __fadd_rn(__fsub_rn(x2s, __fmul_rn(2.0f, a0)), cnorm[kk + 0]);
        float d2_1 = __fadd_rn(__fsub_rn(x2s, __fmul_rn(2.0f, a1)), cnorm[kk + 1]);
        float d2_2 = __fadd_rn(__fsub_rn(x2s, __fmul_rn(2.0f, a2)), cnorm[kk + 2]);
        float d2_3 = __fadd_rn(__fsub_rn(x2s, __fmul_rn(2.0f, a3)), cnorm[kk + 3]);
        bool p;
        p = d2_0 < best; best = p ? d2_0 : best; bidx = p ? kk + 0 : bidx;
        p = d2_1 < best; best = p ? d2_1 : best; bidx = p ? kk + 1 : bidx;
        p = d2_2 < best; best = p ? d2_2 : best; bidx = p ? kk + 2 : bidx;
        p = d2_3 < best; best = p ? d2_3 : best; bidx = p ? kk + 3 : bidx;
    }

    // gather chosen code; STE o = fl(x + fl(q - x)); loss in fp64
    double ls = 0.0;
    {
        const float4* qv = (const float4*)(cb + ((size_t)bidx << 6));
        float4* o = (float4*)(out + (size_t)t * DIM);
#define EPIQ(i, a, b, c, d) { \
        float4 q = qv[i]; float4 ov; float e; \
        e = __fsub_rn(q.x, x##a); ov.x = __fadd_rn(x##a, e); ls += (double)e * e; \
        e = __fsub_rn(q.y, x##b); ov.y = __fadd_rn(x##b, e); ls += (double)e * e; \
        e = __fsub_rn(q.z, x##c); ov.z = __fadd_rn(x##c, e); ls += (double)e * e; \
        e = __fsub_rn(q.w, x##d); ov.w = __fadd_rn(x##d, e); ls += (double)e * e; \
        o[i] = ov; }
        EPIQ(0, 0, 1, 2, 3)    EPIQ(1, 4, 5, 6, 7)    EPIQ(2, 8, 9, 10, 11)
        EPIQ(3, 12, 13, 14, 15) EPIQ(4, 16, 17, 18, 19) EPIQ(5, 20, 21, 22, 23)
        EPIQ(6, 24, 25, 26, 27) EPIQ(7, 28, 29, 30, 31) EPIQ(8, 32, 33, 34, 35)
        EPIQ(9, 36, 37, 38, 39) EPIQ(10, 40, 41, 42, 43) EPIQ(11, 44, 45, 46, 47)
        EPIQ(12, 48, 49, 50, 51) EPIQ(13, 52, 53, 54, 55) EPIQ(14, 56, 57, 58, 59)
        EPIQ(15, 60, 61, 62, 63)
#undef EPIQ
    }

    // block reduce -> one double atomic per block
    for (int off = 32; off > 0; off >>= 1) ls += __shfl_down(ls, off, 64);
    __shared__ double wsum[4];
    const int lane = threadIdx.x & 63, wid = threadIdx.x >> 6;
    if (lane == 0) wsum[wid] = ls;
    __syncthreads();
    if (threadIdx.x == 0)
        atomicAdd(loss_acc, (wsum[0] + wsum[1]) + (wsum[2] + wsum[3]));
}

__global__ void vq_final(const double* __restrict__ loss_acc,
                         float* __restrict__ out_loss)
{
    if (threadIdx.x == 0 && blockIdx.x == 0) {
        double mean = *loss_acc / (double)((size_t)N_TOK * DIM);
        *out_loss = (float)(1.25 * mean);   // beta*commit + codebook, forward-equal
    }
}

extern "C" void kernel_launch(void* const* d_in, const int* in_sizes, int n_in,
                              void* d_out, int out_size, void* d_ws, size_t ws_size,
                              hipStream_t stream) {
    const float* x  = (const float*)d_in[0];
    const float* cb = (const float*)d_in[1];
    float* out = (float*)d_out;
    float* out_loss = out + (size_t)N_TOK * DIM;

    char* ws = (char*)d_ws;
    double* loss_acc = (double*)ws;          // [0,8)
    float* cnorm = (float*)(ws + 64);        // 512 floats

    hipMemsetAsync(d_ws, 0, 16, stream);
    vq_prep<<<2, 256, 0, stream>>>(cb, cnorm);
    vq_main<<<N_TOK / 256, 256, 0, stream>>>(x, cb, cnorm, out, loss_acc);
    vq_final<<<1, 64, 0, stream>>>(loss_acc, out_loss);
}

// Round 5
// 258.591 us; speedup vs baseline: 1.1395x; 1.1395x over previous
//
#include <hip/hip_runtime.h>

#define N_TOK 131072
#define K_CODES 512
#define DIM 64

#define AS4 __attribute__((address_space(4)))
typedef const AS4 float cfloat;   // constant-AS float: uniform loads -> s_load

// ---- numpy pairwise_sum for n=64 (array version, used by vq_prep only) ----
__device__ __forceinline__ float np_sumsq64(const float* v) {
    float r[8];
#pragma unroll
    for (int j = 0; j < 8; ++j) r[j] = __fmul_rn(v[j], v[j]);
#pragma unroll
    for (int i = 8; i < 64; i += 8) {
#pragma unroll
        for (int j = 0; j < 8; ++j)
            r[j] = __fadd_rn(r[j], __fmul_rn(v[i + j], v[i + j]));
    }
    return __fadd_rn(__fadd_rn(__fadd_rn(r[0], r[1]), __fadd_rn(r[2], r[3])),
                     __fadd_rn(__fadd_rn(r[4], r[5]), __fadd_rn(r[6], r[7])));
}

__global__ __launch_bounds__(256) void vq_prep(const float* __restrict__ cb,
                                               float* __restrict__ cnorm) {
    int k = blockIdx.x * 256 + threadIdx.x;
    if (k < K_CODES) {
        float v[DIM];
#pragma unroll
        for (int d = 0; d < DIM; ++d) v[d] = cb[k * DIM + d];
        cnorm[k] = np_sumsq64(v);
    }
}

// macro utilities ------------------------------------------------------------
#define REP64(M) \
  M(0)  M(1)  M(2)  M(3)  M(4)  M(5)  M(6)  M(7)  \
  M(8)  M(9)  M(10) M(11) M(12) M(13) M(14) M(15) \
  M(16) M(17) M(18) M(19) M(20) M(21) M(22) M(23) \
  M(24) M(25) M(26) M(27) M(28) M(29) M(30) M(31) \
  M(32) M(33) M(34) M(35) M(36) M(37) M(38) M(39) \
  M(40) M(41) M(42) M(43) M(44) M(45) M(46) M(47) \
  M(48) M(49) M(50) M(51) M(52) M(53) M(54) M(55) \
  M(56) M(57) M(58) M(59) M(60) M(61) M(62) M(63)

__global__ __attribute__((amdgpu_flat_work_group_size(256, 256),
                          amdgpu_waves_per_eu(2, 2)))
void vq_main(const float* __restrict__ x, const float* __restrict__ cb,
             const float* __restrict__ cnorm, float* __restrict__ out,
             double* __restrict__ loss_acc)
{
    const int t = blockIdx.x * 256 + threadIdx.x;

    // constant-AS views of the (read-only) codebook + norms: uniform address
    // -> scalar loads (s_load), FMA reads SGPR operand directly.
    const cfloat* cbc = (const cfloat*)(unsigned long long)cb;
    const cfloat* cnc = (const cfloat*)(unsigned long long)cnorm;

    const float4* xv = (const float4*)(x + (size_t)t * DIM);
    float4 v0 = xv[0],  v1 = xv[1],  v2 = xv[2],  v3 = xv[3],
           v4 = xv[4],  v5 = xv[5],  v6 = xv[6],  v7 = xv[7],
           v8 = xv[8],  v9 = xv[9],  v10 = xv[10], v11 = xv[11],
           v12 = xv[12], v13 = xv[13], v14 = xv[14], v15 = xv[15];
#define XQ(i, a, b, c, d) \
    float x##a = v##i.x, x##b = v##i.y, x##c = v##i.z, x##d = v##i.w;
    XQ(0, 0, 1, 2, 3)    XQ(1, 4, 5, 6, 7)    XQ(2, 8, 9, 10, 11)
    XQ(3, 12, 13, 14, 15) XQ(4, 16, 17, 18, 19) XQ(5, 20, 21, 22, 23)
    XQ(6, 24, 25, 26, 27) XQ(7, 28, 29, 30, 31) XQ(8, 32, 33, 34, 35)
    XQ(9, 36, 37, 38, 39) XQ(10, 40, 41, 42, 43) XQ(11, 44, 45, 46, 47)
    XQ(12, 48, 49, 50, 51) XQ(13, 52, 53, 54, 55) XQ(14, 56, 57, 58, 59)
    XQ(15, 60, 61, 62, 63)
#undef XQ

    // x2: numpy pairwise_sum order, terms fl(x*x), strict IEEE (no contract)
    float r0 = __fmul_rn(x0, x0), r1 = __fmul_rn(x1, x1),
          r2 = __fmul_rn(x2, x2), r3 = __fmul_rn(x3, x3),
          r4 = __fmul_rn(x4, x4), r5 = __fmul_rn(x5, x5),
          r6 = __fmul_rn(x6, x6), r7 = __fmul_rn(x7, x7);
#define SQROW(a, b, c, d, e, f, g, h) \
    r0 = __fadd_rn(r0, __fmul_rn(x##a, x##a)); \
    r1 = __fadd_rn(r1, __fmul_rn(x##b, x##b)); \
    r2 = __fadd_rn(r2, __fmul_rn(x##c, x##c)); \
    r3 = __fadd_rn(r3, __fmul_rn(x##d, x##d)); \
    r4 = __fadd_rn(r4, __fmul_rn(x##e, x##e)); \
    r5 = __fadd_rn(r5, __fmul_rn(x##f, x##f)); \
    r6 = __fadd_rn(r6, __fmul_rn(x##g, x##g)); \
    r7 = __fadd_rn(r7, __fmul_rn(x##h, x##h));
    SQROW(8, 9, 10, 11, 12, 13, 14, 15)
    SQROW(16, 17, 18, 19, 20, 21, 22, 23)
    SQROW(24, 25, 26, 27, 28, 29, 30, 31)
    SQROW(32, 33, 34, 35, 36, 37, 38, 39)
    SQROW(40, 41, 42, 43, 44, 45, 46, 47)
    SQROW(48, 49, 50, 51, 52, 53, 54, 55)
    SQROW(56, 57, 58, 59, 60, 61, 62, 63)
#undef SQROW
    const float x2s =
        __fadd_rn(__fadd_rn(__fadd_rn(r0, r1), __fadd_rn(r2, r3)),
                  __fadd_rn(__fadd_rn(r4, r5), __fadd_rn(r6, r7)));

    // screen all K codes, 4 independent serial FMA chains (d ascending ==
    // BLAS sgemm microkernel order; bit-exact vs np since R2, absmax 0.0)
    float best = __int_as_float(0x7f800000);  // +inf
    int bidx = 0;
    for (int kg = 0; kg < K_CODES; kg += 4) {
        const int kk = __builtin_amdgcn_readfirstlane(kg);  // uniform
        const cfloat* cA = cbc + ((size_t)kk << 6);
        const cfloat* cB = cA + 64;
        const cfloat* cC = cA + 128;
        const cfloat* cD = cA + 192;
        float a0 = 0.f, a1 = 0.f, a2 = 0.f, a3 = 0.f;
#define FMA_D(d) \
        a0 = __fmaf_rn(x##d, cA[d], a0); \
        a1 = __fmaf_rn(x##d, cB[d], a1); \
        a2 = __fmaf_rn(x##d, cC[d], a2); \
        a3 = __fmaf_rn(x##d, cD[d], a3);
        REP64(FMA_D)
#undef FMA_D
        float d2_0 = __fadd_rn(__fsub_rn(x2s, __fmul_rn(2.0f, a0)), cnc[kk + 0]);
        float d2_1 = __fadd_rn(__fsub_rn(x2s, __fmul_rn(2.0f, a1)), cnc[kk + 1]);
        float d2_2 = __fadd_rn(__fsub_rn(x2s, __fmul_rn(2.0f, a2)), cnc[kk + 2]);
        float d2_3 = __fadd_rn(__fsub_rn(x2s, __fmul_rn(2.0f, a3)), cnc[kk + 3]);
        bool p;
        p = d2_0 < best; best = p ? d2_0 : best; bidx = p ? kk + 0 : bidx;
        p = d2_1 < best; best = p ? d2_1 : best; bidx = p ? kk + 1 : bidx;
        p = d2_2 < best; best = p ? d2_2 : best; bidx = p ? kk + 2 : bidx;
        p = d2_3 < best; best = p ? d2_3 : best; bidx = p ? kk + 3 : bidx;
    }

    // ---- epilogue: STE o = fl(x + fl(q - x)); loss fp64; LDS-staged stores
    // tile stride 65 floats: bank = (row + col) mod 32 -> only 2-way aliasing
    __shared__ float tile[256 * 65];
    double ls = 0.0;
    {
        const float4* qv = (const float4*)(cb + ((size_t)bidx << 6));  // gather
        const int trow = threadIdx.x * 65;
#define EPIQ(i, a, b, c, d) { \
        float4 q = qv[i]; float e; \
        e = __fsub_rn(q.x, x##a); tile[trow + (a)] = __fadd_rn(x##a, e); ls += (double)e * e; \
        e = __fsub_rn(q.y, x##b); tile[trow + (b)] = __fadd_rn(x##b, e); ls += (double)e * e; \
        e = __fsub_rn(q.z, x##c); tile[trow + (c)] = __fadd_rn(x##c, e); ls += (double)e * e; \
        e = __fsub_rn(q.w, x##d); tile[trow + (d)] = __fadd_rn(x##d, e); ls += (double)e * e; }
        EPIQ(0, 0, 1, 2, 3)    EPIQ(1, 4, 5, 6, 7)    EPIQ(2, 8, 9, 10, 11)
        EPIQ(3, 12, 13, 14, 15) EPIQ(4, 16, 17, 18, 19) EPIQ(5, 20, 21, 22, 23)
        EPIQ(6, 24, 25, 26, 27) EPIQ(7, 28, 29, 30, 31) EPIQ(8, 32, 33, 34, 35)
        EPIQ(9, 36, 37, 38, 39) EPIQ(10, 40, 41, 42, 43) EPIQ(11, 44, 45, 46, 47)
        EPIQ(12, 48, 49, 50, 51) EPIQ(13, 52, 53, 54, 55) EPIQ(14, 56, 57, 58, 59)
        EPIQ(15, 60, 61, 62, 63)
#undef EPIQ
    }
    __syncthreads();

    // cooperative copy-out: per instruction, 64 lanes write 1KB contiguous
    {
        float* ob = out + ((size_t)blockIdx.x << 14);   // block's 16384 floats
#pragma unroll
        for (int i = 0; i < 16; ++i) {
            int f = (i << 8) + threadIdx.x;  // float4 id, lanes consecutive
            int flat = f << 2;
            int row = flat >> 6, col = flat & 63;
            int la = row * 65 + col;
            float4 v;
            v.x = tile[la]; v.y = tile[la + 1];
            v.z = tile[la + 2]; v.w = tile[la + 3];
            *(float4*)(ob + flat) = v;
        }
    }

    // block reduce -> one double atomic per block
    for (int off = 32; off > 0; off >>= 1) ls += __shfl_down(ls, off, 64);
    __shared__ double wsum[4];
    const int lane = threadIdx.x & 63, wid = threadIdx.x >> 6;
    if (lane == 0) wsum[wid] = ls;
    __syncthreads();
    if (threadIdx.x == 0)
        atomicAdd(loss_acc, (wsum[0] + wsum[1]) + (wsum[2] + wsum[3]));
}

__global__ void vq_final(const double* __restrict__ loss_acc,
                         float* __restrict__ out_loss)
{
    if (threadIdx.x == 0 && blockIdx.x == 0) {
        double mean = *loss_acc / (double)((size_t)N_TOK * DIM);
        *out_loss = (float)(1.25 * mean);   // beta*commit + codebook, forward-equal
    }
}

extern "C" void kernel_launch(void* const* d_in, const int* in_sizes, int n_in,
                              void* d_out, int out_size, void* d_ws, size_t ws_size,
                              hipStream_t stream) {
    const float* x  = (const float*)d_in[0];
    const float* cb = (const float*)d_in[1];
    float* out = (float*)d_out;
    float* out_loss = out + (size_t)N_TOK * DIM;

    char* ws = (char*)d_ws;
    double* loss_acc = (double*)ws;          // [0,8)
    float* cnorm = (float*)(ws + 64);        // 512 floats

    hipMemsetAsync(d_ws, 0, 16, stream);
    vq_prep<<<2, 256, 0, stream>>>(cb, cnorm);
    vq_main<<<N_TOK / 256, 256, 0, stream>>>(x, cb, cnorm, out, loss_acc);
    vq_final<<<1, 64, 0, stream>>>(loss_acc, out_loss);
}

// Round 6
// 233.045 us; speedup vs baseline: 1.2645x; 1.1096x over previous
//
#include <hip/hip_runtime.h>

#define N_TOK 131072
#define K_CODES 512
#define DIM 64
#define MARGIN_S 3e-4f     // s = c2/2 - dot units; d2 gap = 2x this
#define LIST_CAP 30000

typedef __attribute__((ext_vector_type(8))) short bfx8;
typedef __attribute__((ext_vector_type(4))) float f32x4;

__device__ __forceinline__ unsigned short f2bf_rn(float f) {
    unsigned u = __float_as_uint(f);
    unsigned r = (u + 0x7FFF + ((u >> 16) & 1)) >> 16;   // RNE (normals only)
    return (unsigned short)r;
}
__device__ __forceinline__ float bf2f(unsigned short h) {
    return __uint_as_float(((unsigned)h) << 16);
}

// numpy pairwise_sum for n=64: 8 strided accumulators + pairwise combine.
__device__ __forceinline__ float np_sumsq64(const float* v) {
    float r[8];
#pragma unroll
    for (int j = 0; j < 8; ++j) r[j] = __fmul_rn(v[j], v[j]);
#pragma unroll
    for (int i = 8; i < 64; i += 8) {
#pragma unroll
        for (int j = 0; j < 8; ++j)
            r[j] = __fadd_rn(r[j], __fmul_rn(v[i + j], v[i + j]));
    }
    return __fadd_rn(__fadd_rn(__fadd_rn(r[0], r[1]), __fadd_rn(r[2], r[3])),
                     __fadd_rn(__fadd_rn(r[4], r[5]), __fadd_rn(r[6], r[7])));
}

// per code: np-exact c2, screening c2/2, and bf16 hi/lo split of the row
__global__ __launch_bounds__(256) void vq_prep(
    const float* __restrict__ cb, float* __restrict__ cnorm,
    float* __restrict__ c2h, unsigned short* __restrict__ cbh,
    unsigned short* __restrict__ cbl)
{
    int k = blockIdx.x * 256 + threadIdx.x;
    if (k >= K_CODES) return;
    float v[DIM];
#pragma unroll
    for (int d = 0; d < DIM; ++d) {
        float f = cb[k * DIM + d];
        v[d] = f;
        unsigned short h = f2bf_rn(f);
        cbh[k * DIM + d] = h;
        cbl[k * DIM + d] = f2bf_rn(__fsub_rn(f, bf2f(h)));
    }
    float c2 = np_sumsq64(v);
    cnorm[k] = c2;
    c2h[k] = __fmul_rn(0.5f, c2);
}

// ---- Phase 1: split-bf16 MFMA screen + epilogue write -----------------------
__global__ __launch_bounds__(256, 4) void vq_screen(
    const float* __restrict__ x, const float* __restrict__ cb,
    const unsigned short* __restrict__ cbh, const unsigned short* __restrict__ cbl,
    const float* __restrict__ c2h, float* __restrict__ out,
    double* __restrict__ loss_acc, int* __restrict__ counter,
    int* __restrict__ list, int cap)
{
    const int wave = (blockIdx.x << 2) + (threadIdx.x >> 6);
    const int lane = threadIdx.x & 63;
    const int tokb = wave << 4;           // 16 tokens per wave
    const int lrow = lane & 15;           // A: token row / B: code col
    const int lgrp = lane >> 4;           // k-chunk selector (8 k's each)

    // load this lane's x fragment elements and split to bf16 hi/lo
    const float* xr = x + ((size_t)(tokb + lrow) << 6) + (lgrp << 3);
    float4 f0 = *(const float4*)xr;          // k = g*8+0..3   (chunk kc=0)
    float4 f1 = *(const float4*)(xr + 4);    // k = g*8+4..7
    float4 f2 = *(const float4*)(xr + 32);   // chunk kc=1
    float4 f3 = *(const float4*)(xr + 36);
    bfx8 ah0, al0, ah1, al1;
#define SPL(F, J, AH, AL) { unsigned short h_ = f2bf_rn(F); \
    (AH)[J] = (short)h_; (AL)[J] = (short)f2bf_rn(__fsub_rn(F, bf2f(h_))); }
    SPL(f0.x, 0, ah0, al0) SPL(f0.y, 1, ah0, al0)
    SPL(f0.z, 2, ah0, al0) SPL(f0.w, 3, ah0, al0)
    SPL(f1.x, 4, ah0, al0) SPL(f1.y, 5, ah0, al0)
    SPL(f1.z, 6, ah0, al0) SPL(f1.w, 7, ah0, al0)
    SPL(f2.x, 0, ah1, al1) SPL(f2.y, 1, ah1, al1)
    SPL(f2.z, 2, ah1, al1) SPL(f2.w, 3, ah1, al1)
    SPL(f3.x, 4, ah1, al1) SPL(f3.y, 5, ah1, al1)
    SPL(f3.z, 6, ah1, al1) SPL(f3.w, 7, ah1, al1)
#undef SPL

    const float inf = __int_as_float(0x7f800000);
    float best0 = inf, best1 = inf, best2 = inf, best3 = inf;
    float sec0 = inf, sec1 = inf, sec2 = inf, sec3 = inf;
    int idx0 = 0, idx1 = 0, idx2 = 0, idx3 = 0;

#pragma unroll 2
    for (int ct = 0; ct < 32; ++ct) {
        const int code = (ct << 4) + lrow;
        const unsigned short* bhp = cbh + (code << 6) + (lgrp << 3);
        const unsigned short* blp = cbl + (code << 6) + (lgrp << 3);
        bfx8 bh0 = *(const bfx8*)bhp;
        bfx8 bh1 = *(const bfx8*)(bhp + 32);
        bfx8 bl0 = *(const bfx8*)blp;
        bfx8 bl1 = *(const bfx8*)(blp + 32);
        float cn = c2h[code];

        f32x4 acc = {0.f, 0.f, 0.f, 0.f};
        acc = __builtin_amdgcn_mfma_f32_16x16x32_bf16(ah0, bh0, acc, 0, 0, 0);
        acc = __builtin_amdgcn_mfma_f32_16x16x32_bf16(ah1, bh1, acc, 0, 0, 0);
        acc = __builtin_amdgcn_mfma_f32_16x16x32_bf16(ah0, bl0, acc, 0, 0, 0);
        acc = __builtin_amdgcn_mfma_f32_16x16x32_bf16(ah1, bl1, acc, 0, 0, 0);
        acc = __builtin_amdgcn_mfma_f32_16x16x32_bf16(al0, bh0, acc, 0, 0, 0);
        acc = __builtin_amdgcn_mfma_f32_16x16x32_bf16(al1, bh1, acc, 0, 0, 0);
        acc = __builtin_amdgcn_mfma_f32_16x16x32_bf16(al0, bl0, acc, 0, 0, 0);
        acc = __builtin_amdgcn_mfma_f32_16x16x32_bf16(al1, bl1, acc, 0, 0, 0);

        float s; bool p;
#define UPD(R) \
        s = cn - acc[R]; p = s < best##R; \
        sec##R = p ? best##R : fminf(sec##R, s); \
        best##R = p ? s : best##R; idx##R = p ? code : idx##R;
        UPD(0) UPD(1) UPD(2) UPD(3)
#undef UPD
    }

    // reduce across the 16 lanes of this lane-group (code dimension);
    // tie (equal value) -> lower index (np.argmin first-occurrence)
#define RED(R) \
    _Pragma("unroll") \
    for (int off = 1; off < 16; off <<= 1) { \
        float ob = __shfl_xor(best##R, off, 64); \
        float os = __shfl_xor(sec##R, off, 64); \
        int   oi = __shfl_xor(idx##R, off, 64); \
        bool take = (ob < best##R) || (ob == best##R && oi < idx##R); \
        float ns = take ? fminf(best##R, os) : fminf(sec##R, ob); \
        best##R = take ? ob : best##R; \
        idx##R  = take ? oi : idx##R; \
        sec##R  = ns; \
    }
    RED(0) RED(1) RED(2) RED(3)
#undef RED

    const int pk0 = idx0 | (((sec0 - best0) < MARGIN_S) ? (1 << 30) : 0);
    const int pk1 = idx1 | (((sec1 - best1) < MARGIN_S) ? (1 << 30) : 0);
    const int pk2 = idx2 | (((sec2 - best2) < MARGIN_S) ? (1 << 30) : 0);
    const int pk3 = idx3 | (((sec3 - best3) < MARGIN_S) ? (1 << 30) : 0);

    // epilogue: token tt = tokb + g*4 + r lives in lanes g*16.. ; D-layout
    // row = (lane>>4)*4 + reg  (m89-verified C/D mapping)
    double ls = 0.0;
#define EPI(G, R, PK) { \
    int fi = __shfl(PK, (G) * 16, 64); \
    int bidx_t = fi & 0xFFFF; int flag_t = fi >> 30; \
    int t = tokb + (G) * 4 + (R); \
    float xv = x[((size_t)t << 6) + lane]; \
    float q  = cb[((size_t)bidx_t << 6) + lane]; \
    float e = __fsub_rn(q, xv); \
    out[((size_t)t << 6) + lane] = __fadd_rn(xv, e); \
    if (!flag_t) ls += (double)e * (double)e; \
    else if (lane == 0) { int pos = atomicAdd(counter, 1); \
                          if (pos < cap) list[pos] = t; } }
    EPI(0, 0, pk0) EPI(0, 1, pk1) EPI(0, 2, pk2) EPI(0, 3, pk3)
    EPI(1, 0, pk0) EPI(1, 1, pk1) EPI(1, 2, pk2) EPI(1, 3, pk3)
    EPI(2, 0, pk0) EPI(2, 1, pk1) EPI(2, 2, pk2) EPI(2, 3, pk3)
    EPI(3, 0, pk0) EPI(3, 1, pk1) EPI(3, 2, pk2) EPI(3, 3, pk3)
#undef EPI

#pragma unroll
    for (int off = 32; off > 0; off >>= 1) ls += __shfl_down(ls, off, 64);
    if (lane == 0) atomicAdd(loss_acc, ls);
}

// ---- Phase 2: np-exact full re-scan of flagged tokens, one wave per token --
__global__ __launch_bounds__(256) void vq_rerank(
    const float* __restrict__ x, const float* __restrict__ cb,
    const float* __restrict__ cnorm, float* __restrict__ out,
    double* __restrict__ loss_acc, const int* __restrict__ counter,
    const int* __restrict__ list, int cap)
{
    int cnt = *counter; if (cnt > cap) cnt = cap;
    const int lane = threadIdx.x & 63;
    const int wid = (blockIdx.x << 2) + (threadIdx.x >> 6);
    const int nw = gridDim.x << 2;
    double ls = 0.0;

    for (int i = wid; i < cnt; i += nw) {
        const int t = list[i];
        float xr[DIM];
        {
            const float4* xv = (const float4*)(x + ((size_t)t << 6));
#pragma unroll
            for (int q = 0; q < 16; ++q) {
                float4 v = xv[q];
                xr[4 * q + 0] = v.x; xr[4 * q + 1] = v.y;
                xr[4 * q + 2] = v.z; xr[4 * q + 3] = v.w;
            }
        }
        const float x2 = np_sumsq64(xr);
        float best = __int_as_float(0x7f800000);
        int bi = 0;
#pragma unroll
        for (int j = 0; j < 8; ++j) {
            const int k = (j << 6) + lane;       // per-lane ascending k
            const float* c = cb + ((size_t)k << 6);
            float a = 0.f;
#pragma unroll
            for (int d = 0; d < DIM; ++d) a = __fmaf_rn(xr[d], c[d], a);
            float d2 = __fadd_rn(__fsub_rn(x2, __fmul_rn(2.0f, a)), cnorm[k]);
            bool p = d2 < best;
            best = p ? d2 : best; bi = p ? k : bi;
        }
#pragma unroll
        for (int off = 1; off < 64; off <<= 1) {
            float ob = __shfl_xor(best, off, 64);
            int   oi = __shfl_xor(bi, off, 64);
            bool take = (ob < best) || (ob == best && oi < bi);
            best = take ? ob : best; bi = take ? oi : bi;
        }
        float xv = x[((size_t)t << 6) + lane];
        float q  = cb[((size_t)bi << 6) + lane];
        float e = __fsub_rn(q, xv);
        out[((size_t)t << 6) + lane] = __fadd_rn(xv, e);
        ls += (double)e * (double)e;
    }
#pragma unroll
    for (int off = 32; off > 0; off >>= 1) ls += __shfl_down(ls, off, 64);
    if (lane == 0 && ls != 0.0) atomicAdd(loss_acc, ls);
}

__global__ void vq_final(const double* __restrict__ loss_acc,
                         float* __restrict__ out_loss)
{
    if (threadIdx.x == 0 && blockIdx.x == 0) {
        double mean = *loss_acc / (double)((size_t)N_TOK * DIM);
        *out_loss = (float)(1.25 * mean);
    }
}

extern "C" void kernel_launch(void* const* d_in, const int* in_sizes, int n_in,
                              void* d_out, int out_size, void* d_ws, size_t ws_size,
                              hipStream_t stream) {
    const float* x  = (const float*)d_in[0];
    const float* cb = (const float*)d_in[1];
    float* out = (float*)d_out;
    float* out_loss = out + (size_t)N_TOK * DIM;

    char* ws = (char*)d_ws;
    double* loss_acc = (double*)ws;                       // [0,8)
    int* counter = (int*)(ws + 8);                        // [8,12)
    float* cnorm = (float*)(ws + 64);                     // 2KB
    float* c2h = (float*)(ws + 2112);                     // 2KB
    unsigned short* cbh = (unsigned short*)(ws + 4608);   // 64KB
    unsigned short* cbl = (unsigned short*)(ws + 70144);  // 64KB
    int* list = (int*)(ws + 135680);                      // 120KB

    hipMemsetAsync(d_ws, 0, 16, stream);
    vq_prep<<<2, 256, 0, stream>>>(cb, cnorm, c2h, cbh, cbl);
    vq_screen<<<N_TOK / 64, 256, 0, stream>>>(x, cb, cbh, cbl, c2h, out,
                                              loss_acc, counter, list, LIST_CAP);
    vq_rerank<<<128, 256, 0, stream>>>(x, cb, cnorm, out, loss_acc,
                                       counter, list, LIST_CAP);
    vq_final<<<1, 64, 0, stream>>>(loss_acc, out_loss);
}

// Round 7
// 122.511 us; speedup vs baseline: 2.4053x; 1.9022x over previous
//
#include <hip/hip_runtime.h>

#define N_TOK 131072
#define K_CODES 512
#define DIM 64
#define MARGIN_S 3e-4f     // s = c2/2 - dot units; d2 gap = 2x this
#define LIST_CAP 30000

typedef __attribute__((ext_vector_type(8))) short bfx8;
typedef __attribute__((ext_vector_type(4))) float f32x4;
typedef __attribute__((ext_vector_type(4))) int i32x4;

__device__ __forceinline__ unsigned short f2bf_rn(float f) {
    unsigned u = __float_as_uint(f);
    unsigned r = (u + 0x7FFF + ((u >> 16) & 1)) >> 16;   // RNE (normals only)
    return (unsigned short)r;
}
__device__ __forceinline__ float bf2f(unsigned short h) {
    return __uint_as_float(((unsigned)h) << 16);
}

// numpy pairwise_sum for n=64: 8 strided accumulators + pairwise combine.
__device__ __forceinline__ float np_sumsq64(const float* v) {
    float r[8];
#pragma unroll
    for (int j = 0; j < 8; ++j) r[j] = __fmul_rn(v[j], v[j]);
#pragma unroll
    for (int i = 8; i < 64; i += 8) {
#pragma unroll
        for (int j = 0; j < 8; ++j)
            r[j] = __fadd_rn(r[j], __fmul_rn(v[i + j], v[i + j]));
    }
    return __fadd_rn(__fadd_rn(__fadd_rn(r[0], r[1]), __fadd_rn(r[2], r[3])),
                     __fadd_rn(__fadd_rn(r[4], r[5]), __fadd_rn(r[6], r[7])));
}

// per code: np-exact c2, screening c2/2, and bf16 hi/lo split of the row
__global__ __launch_bounds__(256) void vq_prep(
    const float* __restrict__ cb, float* __restrict__ cnorm,
    float* __restrict__ c2h, unsigned short* __restrict__ cbh,
    unsigned short* __restrict__ cbl)
{
    int k = blockIdx.x * 256 + threadIdx.x;
    if (k >= K_CODES) return;
    float v[DIM];
#pragma unroll
    for (int d = 0; d < DIM; ++d) {
        float f = cb[k * DIM + d];
        v[d] = f;
        unsigned short h = f2bf_rn(f);
        cbh[k * DIM + d] = h;
        cbl[k * DIM + d] = f2bf_rn(__fsub_rn(f, bf2f(h)));
    }
    float c2 = np_sumsq64(v);
    cnorm[k] = c2;
    c2h[k] = __fmul_rn(0.5f, c2);
}

// ---- Phase 1: split-bf16 MFMA screen, 64 tokens/wave ------------------------
__global__ __attribute__((amdgpu_flat_work_group_size(256, 256),
                          amdgpu_waves_per_eu(2, 2)))
void vq_screen(
    const float* __restrict__ x, const float* __restrict__ cb,
    const unsigned short* __restrict__ cbh, const unsigned short* __restrict__ cbl,
    const float* __restrict__ c2h, float* __restrict__ out,
    double* __restrict__ loss_acc, int* __restrict__ counter,
    int* __restrict__ list, int cap)
{
    const int wave = (blockIdx.x << 2) + (threadIdx.x >> 6);
    const int lane = threadIdx.x & 63;
    const int tokb = wave << 6;           // 64 tokens per wave
    const int lrow = lane & 15;           // A: token row / B: code col
    const int lgrp = lane >> 4;           // k-chunk selector (8 k's each)
    const int lcol = lrow;                // epilogue: dim quad selector

    const float inf = __int_as_float(0x7f800000);

    // ---- load A fragments for 4 token tiles, split to bf16 hi/lo ----
#define SPL(F, J, AH, AL) { unsigned short h_ = f2bf_rn(F); \
    (AH)[J] = (short)h_; (AL)[J] = (short)f2bf_rn(__fsub_rn(F, bf2f(h_))); }
#define LOADX(m) \
    bfx8 ah0_##m, al0_##m, ah1_##m, al1_##m; \
    { const float* xr = x + ((size_t)(tokb + (m) * 16 + lrow) << 6) + (lgrp << 3); \
      float4 f0 = *(const float4*)xr; \
      float4 f1 = *(const float4*)(xr + 4); \
      float4 f2 = *(const float4*)(xr + 32); \
      float4 f3 = *(const float4*)(xr + 36); \
      SPL(f0.x, 0, ah0_##m, al0_##m) SPL(f0.y, 1, ah0_##m, al0_##m) \
      SPL(f0.z, 2, ah0_##m, al0_##m) SPL(f0.w, 3, ah0_##m, al0_##m) \
      SPL(f1.x, 4, ah0_##m, al0_##m) SPL(f1.y, 5, ah0_##m, al0_##m) \
      SPL(f1.z, 6, ah0_##m, al0_##m) SPL(f1.w, 7, ah0_##m, al0_##m) \
      SPL(f2.x, 0, ah1_##m, al1_##m) SPL(f2.y, 1, ah1_##m, al1_##m) \
      SPL(f2.z, 2, ah1_##m, al1_##m) SPL(f2.w, 3, ah1_##m, al1_##m) \
      SPL(f3.x, 4, ah1_##m, al1_##m) SPL(f3.y, 5, ah1_##m, al1_##m) \
      SPL(f3.z, 6, ah1_##m, al1_##m) SPL(f3.w, 7, ah1_##m, al1_##m) }
    LOADX(0) LOADX(1) LOADX(2) LOADX(3)
#undef LOADX
#undef SPL

    f32x4 best0 = {inf, inf, inf, inf}, best1 = best0, best2 = best0, best3 = best0;
    f32x4 sec0 = best0, sec1 = best0, sec2 = best0, sec3 = best0;
    i32x4 idx0 = {0, 0, 0, 0}, idx1 = idx0, idx2 = idx0, idx3 = idx0;

#pragma unroll 2
    for (int ct = 0; ct < 32; ++ct) {
        const int code = (ct << 4) + lrow;
        const unsigned short* bhp = cbh + (code << 6) + (lgrp << 3);
        const unsigned short* blp = cbl + (code << 6) + (lgrp << 3);
        bfx8 bh0 = *(const bfx8*)bhp;
        bfx8 bh1 = *(const bfx8*)(bhp + 32);
        bfx8 bl0 = *(const bfx8*)blp;
        bfx8 bl1 = *(const bfx8*)(blp + 32);
        float cn = c2h[code];

#define MACC(m) \
        f32x4 acc##m = {0.f, 0.f, 0.f, 0.f}; \
        acc##m = __builtin_amdgcn_mfma_f32_16x16x32_bf16(ah0_##m, bh0, acc##m, 0, 0, 0); \
        acc##m = __builtin_amdgcn_mfma_f32_16x16x32_bf16(ah1_##m, bh1, acc##m, 0, 0, 0); \
        acc##m = __builtin_amdgcn_mfma_f32_16x16x32_bf16(ah0_##m, bl0, acc##m, 0, 0, 0); \
        acc##m = __builtin_amdgcn_mfma_f32_16x16x32_bf16(ah1_##m, bl1, acc##m, 0, 0, 0); \
        acc##m = __builtin_amdgcn_mfma_f32_16x16x32_bf16(al0_##m, bh0, acc##m, 0, 0, 0); \
        acc##m = __builtin_amdgcn_mfma_f32_16x16x32_bf16(al1_##m, bh1, acc##m, 0, 0, 0); \
        acc##m = __builtin_amdgcn_mfma_f32_16x16x32_bf16(al0_##m, bl0, acc##m, 0, 0, 0); \
        acc##m = __builtin_amdgcn_mfma_f32_16x16x32_bf16(al1_##m, bl1, acc##m, 0, 0, 0);
        MACC(0) MACC(1) MACC(2) MACC(3)
#undef MACC

#define UPD1(m, R) { float s = cn - acc##m[R]; bool p = s < best##m[R]; \
        sec##m[R] = p ? best##m[R] : fminf(sec##m[R], s); \
        best##m[R] = p ? s : best##m[R]; \
        idx##m[R] = p ? code : idx##m[R]; }
#define UPDM(m) UPD1(m, 0) UPD1(m, 1) UPD1(m, 2) UPD1(m, 3)
        UPDM(0) UPDM(1) UPDM(2) UPDM(3)
#undef UPDM
#undef UPD1
    }

    // reduce across the 16 lanes of each group (code dimension); tie -> lower
    // index (np.argmin first-occurrence). pk = idx | flag<<30.
    i32x4 pk0, pk1, pk2, pk3;
#define REDR(m, R) { float b = best##m[R], sc = sec##m[R]; int ix = idx##m[R]; \
    _Pragma("unroll") \
    for (int off = 1; off < 16; off <<= 1) { \
        float ob = __shfl_xor(b, off, 64); \
        float os = __shfl_xor(sc, off, 64); \
        int   oi = __shfl_xor(ix, off, 64); \
        bool take = (ob < b) || (ob == b && oi < ix); \
        float ns = take ? fminf(b, os) : fminf(sc, ob); \
        b = take ? ob : b; ix = take ? oi : ix; sc = ns; } \
    pk##m[R] = ix | (((sc - b) < MARGIN_S) ? (1 << 30) : 0); }
#define REDM(m) REDR(m, 0) REDR(m, 1) REDR(m, 2) REDR(m, 3)
    REDM(0) REDM(1) REDM(2) REDM(3)
#undef REDM
#undef REDR

    // ---- epilogue: per (m,R), each lane-group g handles token m*16+g*4+R,
    // lane covers dims lcol*4..+3 as float4. pk##m[R] already uniform within
    // the group (post-reduction) -> no shfl needed.
    double ls = 0.0;
#define EPI1(m, R) { int fi = pk##m[R]; \
    int bidx_t = fi & 0xFFFF; \
    int t = tokb + (m) * 16 + (lgrp << 2) + (R); \
    float4 xv = *((const float4*)(x + ((size_t)t << 6)) + lcol); \
    float4 qv = *((const float4*)(cb + ((size_t)bidx_t << 6)) + lcol); \
    float4 ov; \
    float e0 = __fsub_rn(qv.x, xv.x); ov.x = __fadd_rn(xv.x, e0); \
    float e1 = __fsub_rn(qv.y, xv.y); ov.y = __fadd_rn(xv.y, e1); \
    float e2 = __fsub_rn(qv.z, xv.z); ov.z = __fadd_rn(xv.z, e2); \
    float e3 = __fsub_rn(qv.w, xv.w); ov.w = __fadd_rn(xv.w, e3); \
    *((float4*)(out + ((size_t)t << 6)) + lcol) = ov; \
    if (!(fi >> 30)) \
        ls += (double)e0 * e0 + (double)e1 * e1 + (double)e2 * e2 + (double)e3 * e3; \
    else if (lcol == 0) { int pos = atomicAdd(counter, 1); \
                          if (pos < cap) list[pos] = t; } }
#define EPIM(m) EPI1(m, 0) EPI1(m, 1) EPI1(m, 2) EPI1(m, 3)
    EPIM(0) EPIM(1) EPIM(2) EPIM(3)
#undef EPIM
#undef EPI1

#pragma unroll
    for (int off = 32; off > 0; off >>= 1) ls += __shfl_down(ls, off, 64);
    if (lane == 0) atomicAdd(loss_acc, ls);
}

// ---- Phase 2: np-exact full re-scan of flagged tokens, one wave per token --
__global__ __launch_bounds__(256) void vq_rerank(
    const float* __restrict__ x, const float* __restrict__ cb,
    const float* __restrict__ cnorm, float* __restrict__ out,
    double* __restrict__ loss_acc, const int* __restrict__ counter,
    const int* __restrict__ list, int cap)
{
    int cnt = *counter; if (cnt > cap) cnt = cap;
    const int lane = threadIdx.x & 63;
    const int wid = (blockIdx.x << 2) + (threadIdx.x >> 6);
    const int nw = gridDim.x << 2;
    double ls = 0.0;

    for (int i = wid; i < cnt; i += nw) {
        const int t = list[i];
        float xr[DIM];
        {
            const float4* xv = (const float4*)(x + ((size_t)t << 6));
#pragma unroll
            for (int q = 0; q < 16; ++q) {
                float4 v = xv[q];
                xr[4 * q + 0] = v.x; xr[4 * q + 1] = v.y;
                xr[4 * q + 2] = v.z; xr[4 * q + 3] = v.w;
            }
        }
        const float x2 = np_sumsq64(xr);
        float best = __int_as_float(0x7f800000);
        int bi = 0;
#pragma unroll
        for (int j = 0; j < 8; ++j) {
            const int k = (j << 6) + lane;       // per-lane ascending k
            const float* c = cb + ((size_t)k << 6);
            float a = 0.f;
#pragma unroll
            for (int d = 0; d < DIM; ++d) a = __fmaf_rn(xr[d], c[d], a);
            float d2 = __fadd_rn(__fsub_rn(x2, __fmul_rn(2.0f, a)), cnorm[k]);
            bool p = d2 < best;
            best = p ? d2 : best; bi = p ? k : bi;
        }
#pragma unroll
        for (int off = 1; off < 64; off <<= 1) {
            float ob = __shfl_xor(best, off, 64);
            int   oi = __shfl_xor(bi, off, 64);
            bool take = (ob < best) || (ob == best && oi < bi);
            best = take ? ob : best; bi = take ? oi : bi;
        }
        float xv = x[((size_t)t << 6) + lane];
        float q  = cb[((size_t)bi << 6) + lane];
        float e = __fsub_rn(q, xv);
        out[((size_t)t << 6) + lane] = __fadd_rn(xv, e);
        ls += (double)e * (double)e;
    }
#pragma unroll
    for (int off = 32; off > 0; off >>= 1) ls += __shfl_down(ls, off, 64);
    if (lane == 0 && ls != 0.0) atomicAdd(loss_acc, ls);
}

__global__ void vq_final(const double* __restrict__ loss_acc,
                         float* __restrict__ out_loss)
{
    if (threadIdx.x == 0 && blockIdx.x == 0) {
        double mean = *loss_acc / (double)((size_t)N_TOK * DIM);
        *out_loss = (float)(1.25 * mean);
    }
}

extern "C" void kernel_launch(void* const* d_in, const int* in_sizes, int n_in,
                              void* d_out, int out_size, void* d_ws, size_t ws_size,
                              hipStream_t stream) {
    const float* x  = (const float*)d_in[0];
    const float* cb = (const float*)d_in[1];
    float* out = (float*)d_out;
    float* out_loss = out + (size_t)N_TOK * DIM;

    char* ws = (char*)d_ws;
    double* loss_acc = (double*)ws;                       // [0,8)
    int* counter = (int*)(ws + 8);                        // [8,12)
    float* cnorm = (float*)(ws + 64);                     // 2KB
    float* c2h = (float*)(ws + 2112);                     // 2KB
    unsigned short* cbh = (unsigned short*)(ws + 4608);   // 64KB
    unsigned short* cbl = (unsigned short*)(ws + 70144);  // 64KB
    int* list = (int*)(ws + 135680);                      // 120KB

    hipMemsetAsync(d_ws, 0, 16, stream);
    vq_prep<<<2, 256, 0, stream>>>(cb, cnorm, c2h, cbh, cbl);
    vq_screen<<<N_TOK / 256, 256, 0, stream>>>(x, cb, cbh, cbl, c2h, out,
                                               loss_acc, counter, list, LIST_CAP);
    vq_rerank<<<256, 256, 0, stream>>>(x, cb, cnorm, out, loss_acc,
                                       counter, list, LIST_CAP);
    vq_final<<<1, 64, 0, stream>>>(loss_acc, out_loss);
}

// Round 8
// 117.215 us; speedup vs baseline: 2.5140x; 1.0452x over previous
//
#include <hip/hip_runtime.h>

#define N_TOK 131072
#define K_CODES 512
#define DIM 64
#define MARGIN_S 3e-4f     // s = c2/2 - dot units; d2 gap = 2x this
#define LIST_CAP 30000

typedef __attribute__((ext_vector_type(8))) short bfx8;
typedef __attribute__((ext_vector_type(4))) float f32x4;
typedef __attribute__((ext_vector_type(4))) int i32x4;

__device__ __forceinline__ unsigned short f2bf_rn(float f) {
    unsigned u = __float_as_uint(f);
    unsigned r = (u + 0x7FFF + ((u >> 16) & 1)) >> 16;   // RNE (normals only)
    return (unsigned short)r;
}
__device__ __forceinline__ float bf2f(unsigned short h) {
    return __uint_as_float(((unsigned)h) << 16);
}

// numpy pairwise_sum for n=64: 8 strided accumulators + pairwise combine.
__device__ __forceinline__ float np_sumsq64(const float* v) {
    float r[8];
#pragma unroll
    for (int j = 0; j < 8; ++j) r[j] = __fmul_rn(v[j], v[j]);
#pragma unroll
    for (int i = 8; i < 64; i += 8) {
#pragma unroll
        for (int j = 0; j < 8; ++j)
            r[j] = __fadd_rn(r[j], __fmul_rn(v[i + j], v[i + j]));
    }
    return __fadd_rn(__fadd_rn(__fadd_rn(r[0], r[1]), __fadd_rn(r[2], r[3])),
                     __fadd_rn(__fadd_rn(r[4], r[5]), __fadd_rn(r[6], r[7])));
}

// per code: np-exact c2, screening c2/2, and bf16 hi/lo split of the row
__global__ __launch_bounds__(256) void vq_prep(
    const float* __restrict__ cb, float* __restrict__ cnorm,
    float* __restrict__ c2h, unsigned short* __restrict__ cbh,
    unsigned short* __restrict__ cbl)
{
    int k = blockIdx.x * 256 + threadIdx.x;
    if (k >= K_CODES) return;
    float v[DIM];
#pragma unroll
    for (int d = 0; d < DIM; ++d) {
        float f = cb[k * DIM + d];
        v[d] = f;
        unsigned short h = f2bf_rn(f);
        cbh[k * DIM + d] = h;
        cbl[k * DIM + d] = f2bf_rn(__fsub_rn(f, bf2f(h)));
    }
    float c2 = np_sumsq64(v);
    cnorm[k] = c2;
    c2h[k] = __fmul_rn(0.5f, c2);
}

// ---- Phase 1: split-bf16 MFMA screen, 64 tokens/wave, LDS-staged codebook --
__global__ __attribute__((amdgpu_flat_work_group_size(256, 256),
                          amdgpu_waves_per_eu(2, 2)))
void vq_screen(
    const float* __restrict__ x, const float* __restrict__ cb,
    const unsigned short* __restrict__ cbh, const unsigned short* __restrict__ cbl,
    const float* __restrict__ c2h, float* __restrict__ out,
    double* __restrict__ loss_acc, int* __restrict__ counter,
    int* __restrict__ list, int cap)
{
    // 256 codes' hi+lo split (64KB) + full c2h (2KB); slot-swizzled:
    // row lr, 16B slot s stored at s ^ (lr&7)  -> 2-way banks on read (free)
    __shared__ bfx8 lds_h[256 * 8];
    __shared__ bfx8 lds_l[256 * 8];
    __shared__ float lds_c2[K_CODES];

    const int tid = threadIdx.x;
    const int wave = (blockIdx.x << 2) + (tid >> 6);
    const int lane = tid & 63;
    const int tokb = wave << 6;           // 64 tokens per wave
    const int lrow = lane & 15;           // A: token row / B: code col
    const int lgrp = lane >> 4;           // k-chunk selector (8 k's each)
    const int lcol = lrow;                // epilogue: dim quad selector
    const int sw = lrow & 7;              // LDS swizzle key

    const float inf = __int_as_float(0x7f800000);

    // stage c2h once (visibility covered by first __syncthreads below)
    if (tid < 128) ((float4*)lds_c2)[tid] = ((const float4*)c2h)[tid];

    // ---- load A fragments for 4 token tiles, split to bf16 hi/lo ----
#define SPL(F, J, AH, AL) { unsigned short h_ = f2bf_rn(F); \
    (AH)[J] = (short)h_; (AL)[J] = (short)f2bf_rn(__fsub_rn(F, bf2f(h_))); }
#define LOADX(m) \
    bfx8 ah0_##m, al0_##m, ah1_##m, al1_##m; \
    { const float* xr = x + ((size_t)(tokb + (m) * 16 + lrow) << 6) + (lgrp << 3); \
      float4 f0 = *(const float4*)xr; \
      float4 f1 = *(const float4*)(xr + 4); \
      float4 f2 = *(const float4*)(xr + 32); \
      float4 f3 = *(const float4*)(xr + 36); \
      SPL(f0.x, 0, ah0_##m, al0_##m) SPL(f0.y, 1, ah0_##m, al0_##m) \
      SPL(f0.z, 2, ah0_##m, al0_##m) SPL(f0.w, 3, ah0_##m, al0_##m) \
      SPL(f1.x, 4, ah0_##m, al0_##m) SPL(f1.y, 5, ah0_##m, al0_##m) \
      SPL(f1.z, 6, ah0_##m, al0_##m) SPL(f1.w, 7, ah0_##m, al0_##m) \
      SPL(f2.x, 0, ah1_##m, al1_##m) SPL(f2.y, 1, ah1_##m, al1_##m) \
      SPL(f2.z, 2, ah1_##m, al1_##m) SPL(f2.w, 3, ah1_##m, al1_##m) \
      SPL(f3.x, 4, ah1_##m, al1_##m) SPL(f3.y, 5, ah1_##m, al1_##m) \
      SPL(f3.z, 6, ah1_##m, al1_##m) SPL(f3.w, 7, ah1_##m, al1_##m) }
    LOADX(0) LOADX(1) LOADX(2) LOADX(3)
#undef LOADX
#undef SPL

    f32x4 best0 = {inf, inf, inf, inf}, best1 = best0, best2 = best0, best3 = best0;
    f32x4 sec0 = best0, sec1 = best0, sec2 = best0, sec3 = best0;
    i32x4 idx0 = {0, 0, 0, 0}, idx1 = idx0, idx2 = idx0, idx3 = idx0;

    for (int ph = 0; ph < 2; ++ph) {
        __syncthreads();   // LDS free (entry / previous phase done)
        {
            // stage 256 codes: 2048 16B chunks per array, 8 iters x 256 thr
            const bfx8* gh = (const bfx8*)cbh + (ph << 11);
            const bfx8* gl = (const bfx8*)cbl + (ph << 11);
#pragma unroll
            for (int it = 0; it < 8; ++it) {
                int g = (it << 8) + tid;
                int code = g >> 3, slot = g & 7;
                int dst = (code << 3) + (slot ^ (code & 7));
                lds_h[dst] = gh[g];
                lds_l[dst] = gl[g];
            }
        }
        __syncthreads();

#pragma unroll 2
        for (int ctl = 0; ctl < 16; ++ctl) {
            const int lr = (ctl << 4) + lrow;        // local code row 0..255
            const int code = (ph << 8) + lr;         // global code id
            const int s0 = lgrp ^ sw;
            const bfx8* sh = lds_h + (lr << 3);
            const bfx8* sl = lds_l + (lr << 3);
            bfx8 bh0 = sh[s0];
            bfx8 bh1 = sh[s0 ^ 4];
            bfx8 bl0 = sl[s0];
            bfx8 bl1 = sl[s0 ^ 4];
            float cn = lds_c2[code];

#define MACC(m) \
            f32x4 acc##m = {0.f, 0.f, 0.f, 0.f}; \
            acc##m = __builtin_amdgcn_mfma_f32_16x16x32_bf16(ah0_##m, bh0, acc##m, 0, 0, 0); \
            acc##m = __builtin_amdgcn_mfma_f32_16x16x32_bf16(ah1_##m, bh1, acc##m, 0, 0, 0); \
            acc##m = __builtin_amdgcn_mfma_f32_16x16x32_bf16(ah0_##m, bl0, acc##m, 0, 0, 0); \
            acc##m = __builtin_amdgcn_mfma_f32_16x16x32_bf16(ah1_##m, bl1, acc##m, 0, 0, 0); \
            acc##m = __builtin_amdgcn_mfma_f32_16x16x32_bf16(al0_##m, bh0, acc##m, 0, 0, 0); \
            acc##m = __builtin_amdgcn_mfma_f32_16x16x32_bf16(al1_##m, bh1, acc##m, 0, 0, 0); \
            acc##m = __builtin_amdgcn_mfma_f32_16x16x32_bf16(al0_##m, bl0, acc##m, 0, 0, 0); \
            acc##m = __builtin_amdgcn_mfma_f32_16x16x32_bf16(al1_##m, bl1, acc##m, 0, 0, 0);
            MACC(0) MACC(1) MACC(2) MACC(3)
#undef MACC

#define UPD1(m, R) { float s = cn - acc##m[R]; bool p = s < best##m[R]; \
            sec##m[R] = p ? best##m[R] : fminf(sec##m[R], s); \
            best##m[R] = p ? s : best##m[R]; \
            idx##m[R] = p ? code : idx##m[R]; }
#define UPDM(m) UPD1(m, 0) UPD1(m, 1) UPD1(m, 2) UPD1(m, 3)
            UPDM(0) UPDM(1) UPDM(2) UPDM(3)
#undef UPDM
#undef UPD1
        }
    }

    // reduce across the 16 lanes of each group (code dimension); tie -> lower
    // index (np.argmin first-occurrence). pk = idx | flag<<30.
    i32x4 pk0, pk1, pk2, pk3;
#define REDR(m, R) { float b = best##m[R], sc = sec##m[R]; int ix = idx##m[R]; \
    _Pragma("unroll") \
    for (int off = 1; off < 16; off <<= 1) { \
        float ob = __shfl_xor(b, off, 64); \
        float os = __shfl_xor(sc, off, 64); \
        int   oi = __shfl_xor(ix, off, 64); \
        bool take = (ob < b) || (ob == b && oi < ix); \
        float ns = take ? fminf(b, os) : fminf(sc, ob); \
        b = take ? ob : b; ix = take ? oi : ix; sc = ns; } \
    pk##m[R] = ix | (((sc - b) < MARGIN_S) ? (1 << 30) : 0); }
#define REDM(m) REDR(m, 0) REDR(m, 1) REDR(m, 2) REDR(m, 3)
    REDM(0) REDM(1) REDM(2) REDM(3)
#undef REDM
#undef REDR

    // ---- epilogue: per (m,R), lane-group g owns token m*16+g*4+R, lane
    // covers dims lcol*4..+3. pk uniform within group -> no shfl needed.
    double ls = 0.0;
#define EPI1(m, R) { int fi = pk##m[R]; \
    int bidx_t = fi & 0xFFFF; \
    int t = tokb + (m) * 16 + (lgrp << 2) + (R); \
    float4 xv = *((const float4*)(x + ((size_t)t << 6)) + lcol); \
    float4 qv = *((const float4*)(cb + ((size_t)bidx_t << 6)) + lcol); \
    float4 ov; \
    float e0 = __fsub_rn(qv.x, xv.x); ov.x = __fadd_rn(xv.x, e0); \
    float e1 = __fsub_rn(qv.y, xv.y); ov.y = __fadd_rn(xv.y, e1); \
    float e2 = __fsub_rn(qv.z, xv.z); ov.z = __fadd_rn(xv.z, e2); \
    float e3 = __fsub_rn(qv.w, xv.w); ov.w = __fadd_rn(xv.w, e3); \
    *((float4*)(out + ((size_t)t << 6)) + lcol) = ov; \
    if (!(fi >> 30)) \
        ls += (double)e0 * e0 + (double)e1 * e1 + (double)e2 * e2 + (double)e3 * e3; \
    else if (lcol == 0) { int pos = atomicAdd(counter, 1); \
                          if (pos < cap) list[pos] = t; } }
#define EPIM(m) EPI1(m, 0) EPI1(m, 1) EPI1(m, 2) EPI1(m, 3)
    EPIM(0) EPIM(1) EPIM(2) EPIM(3)
#undef EPIM
#undef EPI1

#pragma unroll
    for (int off = 32; off > 0; off >>= 1) ls += __shfl_down(ls, off, 64);
    if (lane == 0) atomicAdd(loss_acc, ls);
}

// ---- Phase 2: np-exact full re-scan of flagged tokens, one wave per token --
__global__ __launch_bounds__(256) void vq_rerank(
    const float* __restrict__ x, const float* __restrict__ cb,
    const float* __restrict__ cnorm, float* __restrict__ out,
    double* __restrict__ loss_acc, const int* __restrict__ counter,
    const int* __restrict__ list, int cap)
{
    int cnt = *counter; if (cnt > cap) cnt = cap;
    const int lane = threadIdx.x & 63;
    const int wid = (blockIdx.x << 2) + (threadIdx.x >> 6);
    const int nw = gridDim.x << 2;
    double ls = 0.0;

    for (int i = wid; i < cnt; i += nw) {
        const int t = list[i];
        float xr[DIM];
        {
            const float4* xv = (const float4*)(x + ((size_t)t << 6));
#pragma unroll
            for (int q = 0; q < 16; ++q) {
                float4 v = xv[q];
                xr[4 * q + 0] = v.x; xr[4 * q + 1] = v.y;
                xr[4 * q + 2] = v.z; xr[4 * q + 3] = v.w;
            }
        }
        const float x2 = np_sumsq64(xr);
        float best = __int_as_float(0x7f800000);
        int bi = 0;
#pragma unroll 2
        for (int j = 0; j < 8; ++j) {
            const int k = (j << 6) + lane;       // per-lane ascending k
            const float4* c = (const float4*)(cb + ((size_t)k << 6));
            float a = 0.f;
#pragma unroll
            for (int q = 0; q < 16; ++q) {       // float4 loads, chain d-asc
                float4 f = c[q];
                a = __fmaf_rn(xr[4 * q + 0], f.x, a);
                a = __fmaf_rn(xr[4 * q + 1], f.y, a);
                a = __fmaf_rn(xr[4 * q + 2], f.z, a);
                a = __fmaf_rn(xr[4 * q + 3], f.w, a);
            }
            float d2 = __fadd_rn(__fsub_rn(x2, __fmul_rn(2.0f, a)), cnorm[k]);
            bool p = d2 < best;
            best = p ? d2 : best; bi = p ? k : bi;
        }
#pragma unroll
        for (int off = 1; off < 64; off <<= 1) {
            float ob = __shfl_xor(best, off, 64);
            int   oi = __shfl_xor(bi, off, 64);
            bool take = (ob < best) || (ob == best && oi < bi);
            best = take ? ob : best; bi = take ? oi : bi;
        }
        float xv = x[((size_t)t << 6) + lane];
        float q  = cb[((size_t)bi << 6) + lane];
        float e = __fsub_rn(q, xv);
        out[((size_t)t << 6) + lane] = __fadd_rn(xv, e);
        ls += (double)e * (double)e;
    }
#pragma unroll
    for (int off = 32; off > 0; off >>= 1) ls += __shfl_down(ls, off, 64);
    if (lane == 0 && ls != 0.0) atomicAdd(loss_acc, ls);
}

__global__ void vq_final(const double* __restrict__ loss_acc,
                         float* __restrict__ out_loss)
{
    if (threadIdx.x == 0 && blockIdx.x == 0) {
        double mean = *loss_acc / (double)((size_t)N_TOK * DIM);
        *out_loss = (float)(1.25 * mean);
    }
}

extern "C" void kernel_launch(void* const* d_in, const int* in_sizes, int n_in,
                              void* d_out, int out_size, void* d_ws, size_t ws_size,
                              hipStream_t stream) {
    const float* x  = (const float*)d_in[0];
    const float* cb = (const float*)d_in[1];
    float* out = (float*)d_out;
    float* out_loss = out + (size_t)N_TOK * DIM;

    char* ws = (char*)d_ws;
    double* loss_acc = (double*)ws;                       // [0,8)
    int* counter = (int*)(ws + 8);                        // [8,12)
    float* cnorm = (float*)(ws + 64);                     // 2KB
    float* c2h = (float*)(ws + 2112);                     // 2KB
    unsigned short* cbh = (unsigned short*)(ws + 4608);   // 64KB
    unsigned short* cbl = (unsigned short*)(ws + 70144);  // 64KB
    int* list = (int*)(ws + 135680);                      // 120KB

    hipMemsetAsync(d_ws, 0, 16, stream);
    vq_prep<<<2, 256, 0, stream>>>(cb, cnorm, c2h, cbh, cbl);
    vq_screen<<<N_TOK / 256, 256, 0, stream>>>(x, cb, cbh, cbl, c2h, out,
                                               loss_acc, counter, list, LIST_CAP);
    vq_rerank<<<128, 256, 0, stream>>>(x, cb, cnorm, out, loss_acc,
                                       counter, list, LIST_CAP);
    vq_final<<<1, 64, 0, stream>>>(loss_acc, out_loss);
}

// Round 9
// 114.729 us; speedup vs baseline: 2.5684x; 1.0217x over previous
//
#include <hip/hip_runtime.h>

#define N_TOK 131072
#define K_CODES 512
#define DIM 64
#define MARGIN_S 1.5e-4f   // s = c2/2 - dot units; ~5x over ~3e-5 error bound
#define LIST_CAP 30000

typedef __attribute__((ext_vector_type(8))) short bfx8;
typedef __attribute__((ext_vector_type(4))) float f32x4;
typedef __attribute__((ext_vector_type(4))) int i32x4;

__device__ __forceinline__ unsigned short f2bf_rn(float f) {
    unsigned u = __float_as_uint(f);
    unsigned r = (u + 0x7FFF + ((u >> 16) & 1)) >> 16;   // RNE (normals only)
    return (unsigned short)r;
}
__device__ __forceinline__ float bf2f(unsigned short h) {
    return __uint_as_float(((unsigned)h) << 16);
}

// numpy pairwise_sum for n=64: 8 strided accumulators + pairwise combine.
__device__ __forceinline__ float np_sumsq64(const float* v) {
    float r[8];
#pragma unroll
    for (int j = 0; j < 8; ++j) r[j] = __fmul_rn(v[j], v[j]);
#pragma unroll
    for (int i = 8; i < 64; i += 8) {
#pragma unroll
        for (int j = 0; j < 8; ++j)
            r[j] = __fadd_rn(r[j], __fmul_rn(v[i + j], v[i + j]));
    }
    return __fadd_rn(__fadd_rn(__fadd_rn(r[0], r[1]), __fadd_rn(r[2], r[3])),
                     __fadd_rn(__fadd_rn(r[4], r[5]), __fadd_rn(r[6], r[7])));
}

// per code: np-exact c2, screening c2/2, and bf16 hi/lo split of the row
__global__ __launch_bounds__(256) void vq_prep(
    const float* __restrict__ cb, float* __restrict__ cnorm,
    float* __restrict__ c2h, unsigned short* __restrict__ cbh,
    unsigned short* __restrict__ cbl)
{
    int k = blockIdx.x * 256 + threadIdx.x;
    if (k >= K_CODES) return;
    float v[DIM];
#pragma unroll
    for (int d = 0; d < DIM; ++d) {
        float f = cb[k * DIM + d];
        v[d] = f;
        unsigned short h = f2bf_rn(f);
        cbh[k * DIM + d] = h;
        cbl[k * DIM + d] = f2bf_rn(__fsub_rn(f, bf2f(h)));
    }
    float c2 = np_sumsq64(v);
    cnorm[k] = c2;
    c2h[k] = __fmul_rn(0.5f, c2);
}

// ---- Phase 1: split-bf16 MFMA screen, 32 tokens/wave, 128-code LDS phases --
// LDS 34KB -> 4 blocks/CU; grid 1024 -> exactly 4 blocks/CU = 4 waves/SIMD.
__global__ __attribute__((amdgpu_flat_work_group_size(256, 256),
                          amdgpu_waves_per_eu(4, 4)))
void vq_screen(
    const float* __restrict__ x, const float* __restrict__ cb,
    const unsigned short* __restrict__ cbh, const unsigned short* __restrict__ cbl,
    const float* __restrict__ c2h, float* __restrict__ out,
    double* __restrict__ loss_acc, int* __restrict__ counter,
    int* __restrict__ list, int cap)
{
    // 128 codes' hi+lo split (32KB) + full c2h (2KB); slot-swizzled:
    // row lr, 16B slot s stored at s ^ (lr&7) -> 2-way banks on read (free)
    __shared__ bfx8 lds_h[128 * 8];
    __shared__ bfx8 lds_l[128 * 8];
    __shared__ float lds_c2[K_CODES];

    const int tid = threadIdx.x;
    const int wave = (blockIdx.x << 2) + (tid >> 6);
    const int lane = tid & 63;
    const int tokb = wave << 5;           // 32 tokens per wave
    const int lrow = lane & 15;           // A: token row / B: code col
    const int lgrp = lane >> 4;           // k-chunk selector (8 k's each)
    const int lcol = lrow;                // epilogue: dim quad selector
    const int sw = lrow & 7;              // LDS swizzle key

    const float inf = __int_as_float(0x7f800000);

    // stage c2h once (visibility covered by first __syncthreads below)
    if (tid < 128) ((float4*)lds_c2)[tid] = ((const float4*)c2h)[tid];

    // ---- load A fragments for 2 token tiles, split to bf16 hi/lo ----
#define SPL(F, J, AH, AL) { unsigned short h_ = f2bf_rn(F); \
    (AH)[J] = (short)h_; (AL)[J] = (short)f2bf_rn(__fsub_rn(F, bf2f(h_))); }
#define LOADX(m) \
    bfx8 ah0_##m, al0_##m, ah1_##m, al1_##m; \
    { const float* xr = x + ((size_t)(tokb + (m) * 16 + lrow) << 6) + (lgrp << 3); \
      float4 f0 = *(const float4*)xr; \
      float4 f1 = *(const float4*)(xr + 4); \
      float4 f2 = *(const float4*)(xr + 32); \
      float4 f3 = *(const float4*)(xr + 36); \
      SPL(f0.x, 0, ah0_##m, al0_##m) SPL(f0.y, 1, ah0_##m, al0_##m) \
      SPL(f0.z, 2, ah0_##m, al0_##m) SPL(f0.w, 3, ah0_##m, al0_##m) \
      SPL(f1.x, 4, ah0_##m, al0_##m) SPL(f1.y, 5, ah0_##m, al0_##m) \
      SPL(f1.z, 6, ah0_##m, al0_##m) SPL(f1.w, 7, ah0_##m, al0_##m) \
      SPL(f2.x, 0, ah1_##m, al1_##m) SPL(f2.y, 1, ah1_##m, al1_##m) \
      SPL(f2.z, 2, ah1_##m, al1_##m) SPL(f2.w, 3, ah1_##m, al1_##m) \
      SPL(f3.x, 4, ah1_##m, al1_##m) SPL(f3.y, 5, ah1_##m, al1_##m) \
      SPL(f3.z, 6, ah1_##m, al1_##m) SPL(f3.w, 7, ah1_##m, al1_##m) }
    LOADX(0) LOADX(1)
#undef LOADX
#undef SPL

    f32x4 best0 = {inf, inf, inf, inf}, best1 = best0;
    f32x4 sec0 = best0, sec1 = best0;
    i32x4 idx0 = {0, 0, 0, 0}, idx1 = idx0;

    for (int ph = 0; ph < 4; ++ph) {
        __syncthreads();   // LDS free (entry / previous phase done)
        {
            // stage 128 codes: 1024 16B chunks per array, 4 iters x 256 thr
            const bfx8* gh = (const bfx8*)cbh + (ph << 10);
            const bfx8* gl = (const bfx8*)cbl + (ph << 10);
#pragma unroll
            for (int it = 0; it < 4; ++it) {
                int g = (it << 8) + tid;
                int code = g >> 3, slot = g & 7;
                int dst = (code << 3) + (slot ^ (code & 7));
                lds_h[dst] = gh[g];
                lds_l[dst] = gl[g];
            }
        }
        __syncthreads();

#pragma unroll 2
        for (int ctl = 0; ctl < 8; ++ctl) {
            const int lr = (ctl << 4) + lrow;        // local code row 0..127
            const int code = (ph << 7) + lr;         // global code id
            const int s0 = lgrp ^ (lr & 7);
            const bfx8* sh = lds_h + (lr << 3);
            const bfx8* sl = lds_l + (lr << 3);
            bfx8 bh0 = sh[s0];
            bfx8 bh1 = sh[s0 ^ 4];
            bfx8 bl0 = sl[s0];
            bfx8 bl1 = sl[s0 ^ 4];
            float cn = lds_c2[code];

#define MACC(m) \
            f32x4 acc##m = {0.f, 0.f, 0.f, 0.f}; \
            acc##m = __builtin_amdgcn_mfma_f32_16x16x32_bf16(ah0_##m, bh0, acc##m, 0, 0, 0); \
            acc##m = __builtin_amdgcn_mfma_f32_16x16x32_bf16(ah1_##m, bh1, acc##m, 0, 0, 0); \
            acc##m = __builtin_amdgcn_mfma_f32_16x16x32_bf16(ah0_##m, bl0, acc##m, 0, 0, 0); \
            acc##m = __builtin_amdgcn_mfma_f32_16x16x32_bf16(ah1_##m, bl1, acc##m, 0, 0, 0); \
            acc##m = __builtin_amdgcn_mfma_f32_16x16x32_bf16(al0_##m, bh0, acc##m, 0, 0, 0); \
            acc##m = __builtin_amdgcn_mfma_f32_16x16x32_bf16(al1_##m, bh1, acc##m, 0, 0, 0); \
            acc##m = __builtin_amdgcn_mfma_f32_16x16x32_bf16(al0_##m, bl0, acc##m, 0, 0, 0); \
            acc##m = __builtin_amdgcn_mfma_f32_16x16x32_bf16(al1_##m, bl1, acc##m, 0, 0, 0);
            MACC(0) MACC(1)
#undef MACC

#define UPD1(m, R) { float s = cn - acc##m[R]; bool p = s < best##m[R]; \
            sec##m[R] = p ? best##m[R] : fminf(sec##m[R], s); \
            best##m[R] = p ? s : best##m[R]; \
            idx##m[R] = p ? code : idx##m[R]; }
#define UPDM(m) UPD1(m, 0) UPD1(m, 1) UPD1(m, 2) UPD1(m, 3)
            UPDM(0) UPDM(1)
#undef UPDM
#undef UPD1
        }
    }

    // reduce across the 16 lanes of each group (code dimension); tie -> lower
    // index (np.argmin first-occurrence). pk = idx | flag<<30.
    i32x4 pk0, pk1;
#define REDR(m, R) { float b = best##m[R], sc = sec##m[R]; int ix = idx##m[R]; \
    _Pragma("unroll") \
    for (int off = 1; off < 16; off <<= 1) { \
        float ob = __shfl_xor(b, off, 64); \
        float os = __shfl_xor(sc, off, 64); \
        int   oi = __shfl_xor(ix, off, 64); \
        bool take = (ob < b) || (ob == b && oi < ix); \
        float ns = take ? fminf(b, os) : fminf(sc, ob); \
        b = take ? ob : b; ix = take ? oi : ix; sc = ns; } \
    pk##m[R] = ix | (((sc - b) < MARGIN_S) ? (1 << 30) : 0); }
#define REDM(m) REDR(m, 0) REDR(m, 1) REDR(m, 2) REDR(m, 3)
    REDM(0) REDM(1)
#undef REDM
#undef REDR

    // ---- epilogue: per (m,R), lane-group g owns token m*16+g*4+R, lane
    // covers dims lcol*4..+3. pk uniform within group -> no shfl needed.
    double ls = 0.0;
#define EPI1(m, R) { int fi = pk##m[R]; \
    int bidx_t = fi & 0xFFFF; \
    int t = tokb + (m) * 16 + (lgrp << 2) + (R); \
    float4 xv = *((const float4*)(x + ((size_t)t << 6)) + lcol); \
    float4 qv = *((const float4*)(cb + ((size_t)bidx_t << 6)) + lcol); \
    float4 ov; \
    float e0 = __fsub_rn(qv.x, xv.x); ov.x = __fadd_rn(xv.x, e0); \
    float e1 = __fsub_rn(qv.y, xv.y); ov.y = __fadd_rn(xv.y, e1); \
    float e2 = __fsub_rn(qv.z, xv.z); ov.z = __fadd_rn(xv.z, e2); \
    float e3 = __fsub_rn(qv.w, xv.w); ov.w = __fadd_rn(xv.w, e3); \
    *((float4*)(out + ((size_t)t << 6)) + lcol) = ov; \
    if (!(fi >> 30)) \
        ls += (double)e0 * e0 + (double)e1 * e1 + (double)e2 * e2 + (double)e3 * e3; \
    else if (lcol == 0) { int pos = atomicAdd(counter, 1); \
                          if (pos < cap) list[pos] = t; } }
#define EPIM(m) EPI1(m, 0) EPI1(m, 1) EPI1(m, 2) EPI1(m, 3)
    EPIM(0) EPIM(1)
#undef EPIM
#undef EPI1

#pragma unroll
    for (int off = 32; off > 0; off >>= 1) ls += __shfl_down(ls, off, 64);
    if (lane == 0) atomicAdd(loss_acc, ls);
}

// ---- Phase 2: np-exact full re-scan of flagged tokens, one wave per token --
__global__ __launch_bounds__(256) void vq_rerank(
    const float* __restrict__ x, const float* __restrict__ cb,
    const float* __restrict__ cnorm, float* __restrict__ out,
    double* __restrict__ loss_acc, const int* __restrict__ counter,
    const int* __restrict__ list, int cap)
{
    int cnt = *counter; if (cnt > cap) cnt = cap;
    const int lane = threadIdx.x & 63;
    const int wid = (blockIdx.x << 2) + (threadIdx.x >> 6);
    const int nw = gridDim.x << 2;
    double ls = 0.0;

    for (int i = wid; i < cnt; i += nw) {
        const int t = list[i];
        float xr[DIM];
        {
            const float4* xv = (const float4*)(x + ((size_t)t << 6));
#pragma unroll
            for (int q = 0; q < 16; ++q) {
                float4 v = xv[q];
                xr[4 * q + 0] = v.x; xr[4 * q + 1] = v.y;
                xr[4 * q + 2] = v.z; xr[4 * q + 3] = v.w;
            }
        }
        const float x2 = np_sumsq64(xr);
        float best = __int_as_float(0x7f800000);
        int bi = 0;
#pragma unroll 2
        for (int j = 0; j < 8; ++j) {
            const int k = (j << 6) + lane;       // per-lane ascending k
            const float4* c = (const float4*)(cb + ((size_t)k << 6));
            float a = 0.f;
#pragma unroll
            for (int q = 0; q < 16; ++q) {       // float4 loads, chain d-asc
                float4 f = c[q];
                a = __fmaf_rn(xr[4 * q + 0], f.x, a);
                a = __fmaf_rn(xr[4 * q + 1], f.y, a);
                a = __fmaf_rn(xr[4 * q + 2], f.z, a);
                a = __fmaf_rn(xr[4 * q + 3], f.w, a);
            }
            float d2 = __fadd_rn(__fsub_rn(x2, __fmul_rn(2.0f, a)), cnorm[k]);
            bool p = d2 < best;
            best = p ? d2 : best; bi = p ? k : bi;
        }
#pragma unroll
        for (int off = 1; off < 64; off <<= 1) {
            float ob = __shfl_xor(best, off, 64);
            int   oi = __shfl_xor(bi, off, 64);
            bool take = (ob < best) || (ob == best && oi < bi);
            best = take ? ob : best; bi = take ? oi : bi;
        }
        float xv = x[((size_t)t << 6) + lane];
        float q  = cb[((size_t)bi << 6) + lane];
        float e = __fsub_rn(q, xv);
        out[((size_t)t << 6) + lane] = __fadd_rn(xv, e);
        ls += (double)e * (double)e;
    }
#pragma unroll
    for (int off = 32; off > 0; off >>= 1) ls += __shfl_down(ls, off, 64);
    if (lane == 0 && ls != 0.0) atomicAdd(loss_acc, ls);
}

__global__ void vq_final(const double* __restrict__ loss_acc,
                         float* __restrict__ out_loss)
{
    if (threadIdx.x == 0 && blockIdx.x == 0) {
        double mean = *loss_acc / (double)((size_t)N_TOK * DIM);
        *out_loss = (float)(1.25 * mean);
    }
}

extern "C" void kernel_launch(void* const* d_in, const int* in_sizes, int n_in,
                              void* d_out, int out_size, void* d_ws, size_t ws_size,
                              hipStream_t stream) {
    const float* x  = (const float*)d_in[0];
    const float* cb = (const float*)d_in[1];
    float* out = (float*)d_out;
    float* out_loss = out + (size_t)N_TOK * DIM;

    char* ws = (char*)d_ws;
    double* loss_acc = (double*)ws;                       // [0,8)
    int* counter = (int*)(ws + 8);                        // [8,12)
    float* cnorm = (float*)(ws + 64);                     // 2KB
    float* c2h = (float*)(ws + 2112);                     // 2KB
    unsigned short* cbh = (unsigned short*)(ws + 4608);   // 64KB
    unsigned short* cbl = (unsigned short*)(ws + 70144);  // 64KB
    int* list = (int*)(ws + 135680);                      // 120KB

    hipMemsetAsync(d_ws, 0, 16, stream);
    vq_prep<<<2, 256, 0, stream>>>(cb, cnorm, c2h, cbh, cbl);
    vq_screen<<<N_TOK / 128, 256, 0, stream>>>(x, cb, cbh, cbl, c2h, out,
                                               loss_acc, counter, list, LIST_CAP);
    vq_rerank<<<128, 256, 0, stream>>>(x, cb, cnorm, out, loss_acc,
                                       counter, list, LIST_CAP);
    vq_final<<<1, 64, 0, stream>>>(loss_acc, out_loss);
}

// Round 10
// 86.073 us; speedup vs baseline: 3.4235x; 1.3329x over previous
//
#include <hip/hip_runtime.h>

#define N_TOK 131072
#define K_CODES 512
#define DIM 64
#define MARGIN_S 1.5e-4f   // s units; total screen-vs-np error <= ~6e-5
#define LIST_CAP 30000

typedef __attribute__((ext_vector_type(8))) short bfx8;
typedef __attribute__((ext_vector_type(4))) float f32x4;
typedef __attribute__((ext_vector_type(4))) int i32x4;

__device__ __forceinline__ unsigned short f2bf_rn(float f) {
    unsigned u = __float_as_uint(f);
    unsigned r = (u + 0x7FFF + ((u >> 16) & 1)) >> 16;   // RNE (normals only)
    return (unsigned short)r;
}
__device__ __forceinline__ float bf2f(unsigned short h) {
    return __uint_as_float(((unsigned)h) << 16);
}

// numpy pairwise_sum for n=64: 8 strided accumulators + pairwise combine.
__device__ __forceinline__ float np_sumsq64(const float* v) {
    float r[8];
#pragma unroll
    for (int j = 0; j < 8; ++j) r[j] = __fmul_rn(v[j], v[j]);
#pragma unroll
    for (int i = 8; i < 64; i += 8) {
#pragma unroll
        for (int j = 0; j < 8; ++j)
            r[j] = __fadd_rn(r[j], __fmul_rn(v[i + j], v[i + j]));
    }
    return __fadd_rn(__fadd_rn(__fadd_rn(r[0], r[1]), __fadd_rn(r[2], r[3])),
                     __fadd_rn(__fadd_rn(r[4], r[5]), __fadd_rn(r[6], r[7])));
}

// per code: np-exact c2, screening c2/2, and bf16 hi/lo split of the row
__global__ __launch_bounds__(256) void vq_prep(
    const float* __restrict__ cb, float* __restrict__ cnorm,
    float* __restrict__ c2h, unsigned short* __restrict__ cbh,
    unsigned short* __restrict__ cbl)
{
    int k = blockIdx.x * 256 + threadIdx.x;
    if (k >= K_CODES) return;
    float v[DIM];
#pragma unroll
    for (int d = 0; d < DIM; ++d) {
        float f = cb[k * DIM + d];
        v[d] = f;
        unsigned short h = f2bf_rn(f);
        cbh[k * DIM + d] = h;
        cbl[k * DIM + d] = f2bf_rn(__fsub_rn(f, bf2f(h)));
    }
    float c2 = np_sumsq64(v);
    cnorm[k] = c2;
    c2h[k] = __fmul_rn(0.5f, c2);
}

// ---- Phase 1: split-bf16 MFMA screen, 64 tokens/wave, pipelined B reads ----
__global__ __attribute__((amdgpu_flat_work_group_size(256, 256),
                          amdgpu_waves_per_eu(2, 2)))
void vq_screen(
    const float* __restrict__ x, const float* __restrict__ cb,
    const unsigned short* __restrict__ cbh, const unsigned short* __restrict__ cbl,
    const float* __restrict__ c2h, float* __restrict__ out,
    double* __restrict__ loss_acc, int* __restrict__ counter,
    int* __restrict__ list, int cap)
{
    // 128 codes' hi+lo split (32KB) + c2h (2KB); slot-swizzled (x^(row&7))
    __shared__ bfx8 lds_h[128 * 8];
    __shared__ bfx8 lds_l[128 * 8];
    __shared__ float lds_c2[K_CODES];
    __shared__ double wsum[4];

    const int tid = threadIdx.x;
    const int wave = (blockIdx.x << 2) + (tid >> 6);
    const int lane = tid & 63;
    const int tokb = wave << 6;           // 64 tokens per wave
    const int lrow = lane & 15;           // A: token row / B: code col
    const int lgrp = lane >> 4;           // k-chunk selector (8 k's each)
    const int lcol = lrow;                // epilogue: dim quad selector

    const float inf = __int_as_float(0x7f800000);

    if (tid < 128) ((float4*)lds_c2)[tid] = ((const float4*)c2h)[tid];

    // ---- load A fragments for 4 token tiles, split to bf16 hi/lo ----
#define SPL(F, J, AH, AL) { unsigned short h_ = f2bf_rn(F); \
    (AH)[J] = (short)h_; (AL)[J] = (short)f2bf_rn(__fsub_rn(F, bf2f(h_))); }
#define LOADX(m) \
    bfx8 ah0_##m, al0_##m, ah1_##m, al1_##m; \
    { const float* xr = x + ((size_t)(tokb + (m) * 16 + lrow) << 6) + (lgrp << 3); \
      float4 f0 = *(const float4*)xr; \
      float4 f1 = *(const float4*)(xr + 4); \
      float4 f2 = *(const float4*)(xr + 32); \
      float4 f3 = *(const float4*)(xr + 36); \
      SPL(f0.x, 0, ah0_##m, al0_##m) SPL(f0.y, 1, ah0_##m, al0_##m) \
      SPL(f0.z, 2, ah0_##m, al0_##m) SPL(f0.w, 3, ah0_##m, al0_##m) \
      SPL(f1.x, 4, ah0_##m, al0_##m) SPL(f1.y, 5, ah0_##m, al0_##m) \
      SPL(f1.z, 6, ah0_##m, al0_##m) SPL(f1.w, 7, ah0_##m, al0_##m) \
      SPL(f2.x, 0, ah1_##m, al1_##m) SPL(f2.y, 1, ah1_##m, al1_##m) \
      SPL(f2.z, 2, ah1_##m, al1_##m) SPL(f2.w, 3, ah1_##m, al1_##m) \
      SPL(f3.x, 4, ah1_##m, al1_##m) SPL(f3.y, 5, ah1_##m, al1_##m) \
      SPL(f3.z, 6, ah1_##m, al1_##m) SPL(f3.w, 7, ah1_##m, al1_##m) }
    LOADX(0) LOADX(1) LOADX(2) LOADX(3)
#undef LOADX
#undef SPL

    f32x4 best0 = {inf, inf, inf, inf}, best1 = best0, best2 = best0, best3 = best0;
    f32x4 sec0 = best0, sec1 = best0, sec2 = best0, sec3 = best0;
    i32x4 idx0 = {0, 0, 0, 0}, idx1 = idx0, idx2 = idx0, idx3 = idx0;

    for (int ph = 0; ph < 4; ++ph) {
        __syncthreads();   // LDS free (entry / previous phase done)
        {
            const bfx8* gh = (const bfx8*)cbh + (ph << 10);
            const bfx8* gl = (const bfx8*)cbl + (ph << 10);
#pragma unroll
            for (int it = 0; it < 4; ++it) {
                int g = (it << 8) + tid;
                int code = g >> 3, slot = g & 7;
                int dst = (code << 3) + (slot ^ (code & 7));
                lds_h[dst] = gh[g];
                lds_l[dst] = gl[g];
            }
        }
        __syncthreads();

        // pipelined inner loop: issue iter i+1's LDS reads before iter i's
        // MFMA cluster so ds_read latency hides under ~24 MFMAs.
        int lr_c = lrow;                       // ctl=0 local code row
        int s0_c = lgrp ^ (lr_c & 7);
        bfx8 bh0 = lds_h[(lr_c << 3) + s0_c];
        bfx8 bh1 = lds_h[(lr_c << 3) + (s0_c ^ 4)];
        bfx8 bl0 = lds_l[(lr_c << 3) + s0_c];
        bfx8 bl1 = lds_l[(lr_c << 3) + (s0_c ^ 4)];
        float cn = lds_c2[(ph << 7) + lr_c];

#pragma unroll
        for (int ctl = 0; ctl < 8; ++ctl) {
            const int code = (ph << 7) + (ctl << 4) + lrow;
            // prefetch next iter's B + cn
            bfx8 nh0 = bh0, nh1 = bh1, nl0 = bl0, nl1 = bl1;
            float cnn = cn;
            if (ctl < 7) {
                int lr_n = ((ctl + 1) << 4) + lrow;
                int s0_n = lgrp ^ (lr_n & 7);
                nh0 = lds_h[(lr_n << 3) + s0_n];
                nh1 = lds_h[(lr_n << 3) + (s0_n ^ 4)];
                nl0 = lds_l[(lr_n << 3) + s0_n];
                nl1 = lds_l[(lr_n << 3) + (s0_n ^ 4)];
                cnn = lds_c2[(ph << 7) + lr_n];
            }

            // 6 MFMAs per tile: hh(2) + h*l cross terms(4); al*bl dropped
            // (|sum al*bl| <= 2^-16*||x||*||c|| ~ 3e-5 << margin)
#define MACC(m) \
            f32x4 acc##m = {0.f, 0.f, 0.f, 0.f}; \
            acc##m = __builtin_amdgcn_mfma_f32_16x16x32_bf16(ah0_##m, bh0, acc##m, 0, 0, 0); \
            acc##m = __builtin_amdgcn_mfma_f32_16x16x32_bf16(ah1_##m, bh1, acc##m, 0, 0, 0); \
            acc##m = __builtin_amdgcn_mfma_f32_16x16x32_bf16(ah0_##m, bl0, acc##m, 0, 0, 0); \
            acc##m = __builtin_amdgcn_mfma_f32_16x16x32_bf16(ah1_##m, bl1, acc##m, 0, 0, 0); \
            acc##m = __builtin_amdgcn_mfma_f32_16x16x32_bf16(al0_##m, bh0, acc##m, 0, 0, 0); \
            acc##m = __builtin_amdgcn_mfma_f32_16x16x32_bf16(al1_##m, bh1, acc##m, 0, 0, 0);
            MACC(0) MACC(1) MACC(2) MACC(3)
#undef MACC

#define UPD1(m, R) { float s = cn - acc##m[R]; bool p = s < best##m[R]; \
            sec##m[R] = p ? best##m[R] : fminf(sec##m[R], s); \
            best##m[R] = p ? s : best##m[R]; \
            idx##m[R] = p ? code : idx##m[R]; }
#define UPDM(m) UPD1(m, 0) UPD1(m, 1) UPD1(m, 2) UPD1(m, 3)
            UPDM(0) UPDM(1) UPDM(2) UPDM(3)
#undef UPDM
#undef UPD1

            bh0 = nh0; bh1 = nh1; bl0 = nl0; bl1 = nl1; cn = cnn;
        }
    }

    // reduce across the 16 lanes of each group (code dim); tie -> lower index
    i32x4 pk0, pk1, pk2, pk3;
#define REDR(m, R) { float b = best##m[R], sc = sec##m[R]; int ix = idx##m[R]; \
    _Pragma("unroll") \
    for (int off = 1; off < 16; off <<= 1) { \
        float ob = __shfl_xor(b, off, 64); \
        float os = __shfl_xor(sc, off, 64); \
        int   oi = __shfl_xor(ix, off, 64); \
        bool take = (ob < b) || (ob == b && oi < ix); \
        float ns = take ? fminf(b, os) : fminf(sc, ob); \
        b = take ? ob : b; ix = take ? oi : ix; sc = ns; } \
    pk##m[R] = ix | (((sc - b) < MARGIN_S) ? (1 << 30) : 0); }
#define REDM(m) REDR(m, 0) REDR(m, 1) REDR(m, 2) REDR(m, 3)
    REDM(0) REDM(1) REDM(2) REDM(3)
#undef REDM
#undef REDR

    // ---- epilogue: per (m,R), lane-group g owns token m*16+g*4+R ----
    double ls = 0.0;
#define EPI1(m, R) { int fi = pk##m[R]; \
    int bidx_t = fi & 0xFFFF; \
    int t = tokb + (m) * 16 + (lgrp << 2) + (R); \
    float4 xv = *((const float4*)(x + ((size_t)t << 6)) + lcol); \
    float4 qv = *((const float4*)(cb + ((size_t)bidx_t << 6)) + lcol); \
    float4 ov; \
    float e0 = __fsub_rn(qv.x, xv.x); ov.x = __fadd_rn(xv.x, e0); \
    float e1 = __fsub_rn(qv.y, xv.y); ov.y = __fadd_rn(xv.y, e1); \
    float e2 = __fsub_rn(qv.z, xv.z); ov.z = __fadd_rn(xv.z, e2); \
    float e3 = __fsub_rn(qv.w, xv.w); ov.w = __fadd_rn(xv.w, e3); \
    *((float4*)(out + ((size_t)t << 6)) + lcol) = ov; \
    if (!(fi >> 30)) \
        ls += (double)e0 * e0 + (double)e1 * e1 + (double)e2 * e2 + (double)e3 * e3; \
    else if (lcol == 0) { int pos = atomicAdd(counter, 1); \
                          if (pos < cap) list[pos] = t; } }
#define EPIM(m) EPI1(m, 0) EPI1(m, 1) EPI1(m, 2) EPI1(m, 3)
    EPIM(0) EPIM(1) EPIM(2) EPIM(3)
#undef EPIM
#undef EPI1

    // block-level loss reduce -> ONE atomic per block
#pragma unroll
    for (int off = 32; off > 0; off >>= 1) ls += __shfl_down(ls, off, 64);
    if (lane == 0) wsum[tid >> 6] = ls;
    __syncthreads();
    if (tid == 0)
        atomicAdd(loss_acc, (wsum[0] + wsum[1]) + (wsum[2] + wsum[3]));
}

// ---- Phase 2: np-exact full re-scan of flagged tokens, one wave per token --
__global__ __launch_bounds__(256) void vq_rerank(
    const float* __restrict__ x, const float* __restrict__ cb,
    const float* __restrict__ cnorm, float* __restrict__ out,
    double* __restrict__ loss_acc, const int* __restrict__ counter,
    const int* __restrict__ list, int cap)
{
    int cnt = *counter; if (cnt > cap) cnt = cap;
    const int lane = threadIdx.x & 63;
    const int wid = (blockIdx.x << 2) + (threadIdx.x >> 6);
    const int nw = gridDim.x << 2;
    double ls = 0.0;

    for (int i = wid; i < cnt; i += nw) {
        const int t = list[i];
        float xr[DIM];
        {
            const float4* xv = (const float4*)(x + ((size_t)t << 6));
#pragma unroll
            for (int q = 0; q < 16; ++q) {
                float4 v = xv[q];
                xr[4 * q + 0] = v.x; xr[4 * q + 1] = v.y;
                xr[4 * q + 2] = v.z; xr[4 * q + 3] = v.w;
            }
        }
        const float x2 = np_sumsq64(xr);
        float best = __int_as_float(0x7f800000);
        int bi = 0;
#pragma unroll 2
        for (int j = 0; j < 8; ++j) {
            const int k = (j << 6) + lane;       // per-lane ascending k
            const float4* c = (const float4*)(cb + ((size_t)k << 6));
            float a = 0.f;
#pragma unroll
            for (int q = 0; q < 16; ++q) {       // float4 loads, chain d-asc
                float4 f = c[q];
                a = __fmaf_rn(xr[4 * q + 0], f.x, a);
                a = __fmaf_rn(xr[4 * q + 1], f.y, a);
                a = __fmaf_rn(xr[4 * q + 2], f.z, a);
                a = __fmaf_rn(xr[4 * q + 3], f.w, a);
            }
            float d2 = __fadd_rn(__fsub_rn(x2, __fmul_rn(2.0f, a)), cnorm[k]);
            bool p = d2 < best;
            best = p ? d2 : best; bi = p ? k : bi;
        }
#pragma unroll
        for (int off = 1; off < 64; off <<= 1) {
            float ob = __shfl_xor(best, off, 64);
            int   oi = __shfl_xor(bi, off, 64);
            bool take = (ob < best) || (ob == best && oi < bi);
            best = take ? ob : best; bi = take ? oi : bi;
        }
        float xv = x[((size_t)t << 6) + lane];
        float q  = cb[((size_t)bi << 6) + lane];
        float e = __fsub_rn(q, xv);
        out[((size_t)t << 6) + lane] = __fadd_rn(xv, e);
        ls += (double)e * (double)e;
    }
#pragma unroll
    for (int off = 32; off > 0; off >>= 1) ls += __shfl_down(ls, off, 64);
    if (lane == 0 && ls != 0.0) atomicAdd(loss_acc, ls);
}

__global__ void vq_final(const double* __restrict__ loss_acc,
                         float* __restrict__ out_loss)
{
    if (threadIdx.x == 0 && blockIdx.x == 0) {
        double mean = *loss_acc / (double)((size_t)N_TOK * DIM);
        *out_loss = (float)(1.25 * mean);
    }
}

extern "C" void kernel_launch(void* const* d_in, const int* in_sizes, int n_in,
                              void* d_out, int out_size, void* d_ws, size_t ws_size,
                              hipStream_t stream) {
    const float* x  = (const float*)d_in[0];
    const float* cb = (const float*)d_in[1];
    float* out = (float*)d_out;
    float* out_loss = out + (size_t)N_TOK * DIM;

    char* ws = (char*)d_ws;
    double* loss_acc = (double*)ws;                       // [0,8)
    int* counter = (int*)(ws + 8);                        // [8,12)
    float* cnorm = (float*)(ws + 64);                     // 2KB
    float* c2h = (float*)(ws + 2112);                     // 2KB
    unsigned short* cbh = (unsigned short*)(ws + 4608);   // 64KB
    unsigned short* cbl = (unsigned short*)(ws + 70144);  // 64KB
    int* list = (int*)(ws + 135680);                      // 120KB

    hipMemsetAsync(d_ws, 0, 16, stream);
    vq_prep<<<2, 256, 0, stream>>>(cb, cnorm, c2h, cbh, cbl);
    vq_screen<<<N_TOK / 256, 256, 0, stream>>>(x, cb, cbh, cbl, c2h, out,
                                               loss_acc, counter, list, LIST_CAP);
    vq_rerank<<<128, 256, 0, stream>>>(x, cb, cnorm, out, loss_acc,
                                       counter, list, LIST_CAP);
    vq_final<<<1, 64, 0, stream>>>(loss_acc, out_loss);
}

// Round 11
// 84.712 us; speedup vs baseline: 3.4785x; 1.0161x over previous
//
#include <hip/hip_runtime.h>

#define N_TOK 131072
#define K_CODES 512
#define DIM 64
#define MARGIN_S 1e-4f     // s units; screen-vs-np error bound ~2.7e-5 worst
#define LIST_CAP 30000

typedef __attribute__((ext_vector_type(8))) short bfx8;
typedef __attribute__((ext_vector_type(4))) float f32x4;
typedef __attribute__((ext_vector_type(4))) int i32x4;

__device__ __forceinline__ unsigned short f2bf_rn(float f) {
    unsigned u = __float_as_uint(f);
    unsigned r = (u + 0x7FFF + ((u >> 16) & 1)) >> 16;   // RNE (normals only)
    return (unsigned short)r;
}
__device__ __forceinline__ float bf2f(unsigned short h) {
    return __uint_as_float(((unsigned)h) << 16);
}

// numpy pairwise_sum for n=64: 8 strided accumulators + pairwise combine.
__device__ __forceinline__ float np_sumsq64(const float* v) {
    float r[8];
#pragma unroll
    for (int j = 0; j < 8; ++j) r[j] = __fmul_rn(v[j], v[j]);
#pragma unroll
    for (int i = 8; i < 64; i += 8) {
#pragma unroll
        for (int j = 0; j < 8; ++j)
            r[j] = __fadd_rn(r[j], __fmul_rn(v[i + j], v[i + j]));
    }
    return __fadd_rn(__fadd_rn(__fadd_rn(r[0], r[1]), __fadd_rn(r[2], r[3])),
                     __fadd_rn(__fadd_rn(r[4], r[5]), __fadd_rn(r[6], r[7])));
}

// per code: np-exact c2, screening c2/2, and bf16 hi/lo split of the row
__global__ __launch_bounds__(256) void vq_prep(
    const float* __restrict__ cb, float* __restrict__ cnorm,
    float* __restrict__ c2h, unsigned short* __restrict__ cbh,
    unsigned short* __restrict__ cbl)
{
    int k = blockIdx.x * 256 + threadIdx.x;
    if (k >= K_CODES) return;
    float v[DIM];
#pragma unroll
    for (int d = 0; d < DIM; ++d) {
        float f = cb[k * DIM + d];
        v[d] = f;
        unsigned short h = f2bf_rn(f);
        cbh[k * DIM + d] = h;
        cbl[k * DIM + d] = f2bf_rn(__fsub_rn(f, bf2f(h)));
    }
    float c2 = np_sumsq64(v);
    cnorm[k] = c2;
    c2h[k] = __fmul_rn(0.5f, c2);
}

// ---- Phase 1: split-bf16 MFMA screen, 64 tokens/wave, pipelined B reads,
// 2 independent 3-deep MFMA chains per tile (8 chains/wave) -----------------
__global__ __attribute__((amdgpu_flat_work_group_size(256, 256),
                          amdgpu_waves_per_eu(2, 2)))
void vq_screen(
    const float* __restrict__ x, const float* __restrict__ cb,
    const unsigned short* __restrict__ cbh, const unsigned short* __restrict__ cbl,
    const float* __restrict__ c2h, float* __restrict__ out,
    double* __restrict__ loss_acc, int* __restrict__ counter,
    int* __restrict__ list, int cap)
{
    // 128 codes' hi+lo split (32KB) + c2h (2KB); slot-swizzled (x^(row&7))
    __shared__ bfx8 lds_h[128 * 8];
    __shared__ bfx8 lds_l[128 * 8];
    __shared__ float lds_c2[K_CODES];
    __shared__ double wsum[4];

    const int tid = threadIdx.x;
    const int wave = (blockIdx.x << 2) + (tid >> 6);
    const int lane = tid & 63;
    const int tokb = wave << 6;           // 64 tokens per wave
    const int lrow = lane & 15;           // A: token row / B: code col
    const int lgrp = lane >> 4;           // k-chunk selector (8 k's each)
    const int lcol = lrow;                // epilogue: dim quad selector

    const float inf = __int_as_float(0x7f800000);

    if (tid < 128) ((float4*)lds_c2)[tid] = ((const float4*)c2h)[tid];

    // ---- load A fragments for 4 token tiles, split to bf16 hi/lo ----
#define SPL(F, J, AH, AL) { unsigned short h_ = f2bf_rn(F); \
    (AH)[J] = (short)h_; (AL)[J] = (short)f2bf_rn(__fsub_rn(F, bf2f(h_))); }
#define LOADX(m) \
    bfx8 ah0_##m, al0_##m, ah1_##m, al1_##m; \
    { const float* xr = x + ((size_t)(tokb + (m) * 16 + lrow) << 6) + (lgrp << 3); \
      float4 f0 = *(const float4*)xr; \
      float4 f1 = *(const float4*)(xr + 4); \
      float4 f2 = *(const float4*)(xr + 32); \
      float4 f3 = *(const float4*)(xr + 36); \
      SPL(f0.x, 0, ah0_##m, al0_##m) SPL(f0.y, 1, ah0_##m, al0_##m) \
      SPL(f0.z, 2, ah0_##m, al0_##m) SPL(f0.w, 3, ah0_##m, al0_##m) \
      SPL(f1.x, 4, ah0_##m, al0_##m) SPL(f1.y, 5, ah0_##m, al0_##m) \
      SPL(f1.z, 6, ah0_##m, al0_##m) SPL(f1.w, 7, ah0_##m, al0_##m) \
      SPL(f2.x, 0, ah1_##m, al1_##m) SPL(f2.y, 1, ah1_##m, al1_##m) \
      SPL(f2.z, 2, ah1_##m, al1_##m) SPL(f2.w, 3, ah1_##m, al1_##m) \
      SPL(f3.x, 4, ah1_##m, al1_##m) SPL(f3.y, 5, ah1_##m, al1_##m) \
      SPL(f3.z, 6, ah1_##m, al1_##m) SPL(f3.w, 7, ah1_##m, al1_##m) }
    LOADX(0) LOADX(1) LOADX(2) LOADX(3)
#undef LOADX
#undef SPL

    f32x4 best0 = {inf, inf, inf, inf}, best1 = best0, best2 = best0, best3 = best0;
    f32x4 sec0 = best0, sec1 = best0, sec2 = best0, sec3 = best0;
    i32x4 idx0 = {0, 0, 0, 0}, idx1 = idx0, idx2 = idx0, idx3 = idx0;

    for (int ph = 0; ph < 4; ++ph) {
        __syncthreads();   // LDS free (entry / previous phase done)
        {
            const bfx8* gh = (const bfx8*)cbh + (ph << 10);
            const bfx8* gl = (const bfx8*)cbl + (ph << 10);
#pragma unroll
            for (int it = 0; it < 4; ++it) {
                int g = (it << 8) + tid;
                int code = g >> 3, slot = g & 7;
                int dst = (code << 3) + (slot ^ (code & 7));
                lds_h[dst] = gh[g];
                lds_l[dst] = gl[g];
            }
        }
        __syncthreads();

        // pipelined inner loop: issue iter i+1's LDS reads before iter i's
        // MFMA cluster so ds_read latency hides under the MFMA issue window.
        int lr_c = lrow;
        int s0_c = lgrp ^ (lr_c & 7);
        bfx8 bh0 = lds_h[(lr_c << 3) + s0_c];
        bfx8 bh1 = lds_h[(lr_c << 3) + (s0_c ^ 4)];
        bfx8 bl0 = lds_l[(lr_c << 3) + s0_c];
        bfx8 bl1 = lds_l[(lr_c << 3) + (s0_c ^ 4)];
        float cn = lds_c2[(ph << 7) + lr_c];

#pragma unroll
        for (int ctl = 0; ctl < 8; ++ctl) {
            const int code = (ph << 7) + (ctl << 4) + lrow;
            // prefetch next iter's B + cn
            bfx8 nh0 = bh0, nh1 = bh1, nl0 = bl0, nl1 = bl1;
            float cnn = cn;
            if (ctl < 7) {
                int lr_n = ((ctl + 1) << 4) + lrow;
                int s0_n = lgrp ^ (lr_n & 7);
                nh0 = lds_h[(lr_n << 3) + s0_n];
                nh1 = lds_h[(lr_n << 3) + (s0_n ^ 4)];
                nl0 = lds_l[(lr_n << 3) + s0_n];
                nl1 = lds_l[(lr_n << 3) + (s0_n ^ 4)];
                cnn = lds_c2[(ph << 7) + lr_n];
            }

            // 6 MFMAs per tile as TWO independent 3-deep chains (P,Q);
            // al*bl dropped (|sum| <= ~1.7e-5 worst case << margin).
#define MACC(m) \
            f32x4 accP##m = {0.f, 0.f, 0.f, 0.f}; \
            f32x4 accQ##m = {0.f, 0.f, 0.f, 0.f}; \
            accP##m = __builtin_amdgcn_mfma_f32_16x16x32_bf16(ah0_##m, bh0, accP##m, 0, 0, 0); \
            accQ##m = __builtin_amdgcn_mfma_f32_16x16x32_bf16(ah1_##m, bh1, accQ##m, 0, 0, 0); \
            accP##m = __builtin_amdgcn_mfma_f32_16x16x32_bf16(al0_##m, bh0, accP##m, 0, 0, 0); \
            accQ##m = __builtin_amdgcn_mfma_f32_16x16x32_bf16(al1_##m, bh1, accQ##m, 0, 0, 0); \
            accP##m = __builtin_amdgcn_mfma_f32_16x16x32_bf16(ah0_##m, bl0, accP##m, 0, 0, 0); \
            accQ##m = __builtin_amdgcn_mfma_f32_16x16x32_bf16(ah1_##m, bl1, accQ##m, 0, 0, 0);
            MACC(0) MACC(1) MACC(2) MACC(3)
#undef MACC

#define UPD1(m, R) { float s = cn - (accP##m[R] + accQ##m[R]); \
            bool p = s < best##m[R]; \
            sec##m[R] = p ? best##m[R] : fminf(sec##m[R], s); \
            best##m[R] = p ? s : best##m[R]; \
            idx##m[R] = p ? code : idx##m[R]; }
#define UPDM(m) UPD1(m, 0) UPD1(m, 1) UPD1(m, 2) UPD1(m, 3)
            UPDM(0) UPDM(1) UPDM(2) UPDM(3)
#undef UPDM
#undef UPD1

            bh0 = nh0; bh1 = nh1; bl0 = nl0; bl1 = nl1; cn = cnn;
        }
    }

    // reduce across the 16 lanes of each group (code dim); tie -> lower index
    i32x4 pk0, pk1, pk2, pk3;
#define REDR(m, R) { float b = best##m[R], sc = sec##m[R]; int ix = idx##m[R]; \
    _Pragma("unroll") \
    for (int off = 1; off < 16; off <<= 1) { \
        float ob = __shfl_xor(b, off, 64); \
        float os = __shfl_xor(sc, off, 64); \
        int   oi = __shfl_xor(ix, off, 64); \
        bool take = (ob < b) || (ob == b && oi < ix); \
        float ns = take ? fminf(b, os) : fminf(sc, ob); \
        b = take ? ob : b; ix = take ? oi : ix; sc = ns; } \
    pk##m[R] = ix | (((sc - b) < MARGIN_S) ? (1 << 30) : 0); }
#define REDM(m) REDR(m, 0) REDR(m, 1) REDR(m, 2) REDR(m, 3)
    REDM(0) REDM(1) REDM(2) REDM(3)
#undef REDM
#undef REDR

    // ---- epilogue: per (m,R), lane-group g owns token m*16+g*4+R ----
    double ls = 0.0;
#define EPI1(m, R) { int fi = pk##m[R]; \
    int bidx_t = fi & 0xFFFF; \
    int t = tokb + (m) * 16 + (lgrp << 2) + (R); \
    float4 xv = *((const float4*)(x + ((size_t)t << 6)) + lcol); \
    float4 qv = *((const float4*)(cb + ((size_t)bidx_t << 6)) + lcol); \
    float4 ov; \
    float e0 = __fsub_rn(qv.x, xv.x); ov.x = __fadd_rn(xv.x, e0); \
    float e1 = __fsub_rn(qv.y, xv.y); ov.y = __fadd_rn(xv.y, e1); \
    float e2 = __fsub_rn(qv.z, xv.z); ov.z = __fadd_rn(xv.z, e2); \
    float e3 = __fsub_rn(qv.w, xv.w); ov.w = __fadd_rn(xv.w, e3); \
    *((float4*)(out + ((size_t)t << 6)) + lcol) = ov; \
    if (!(fi >> 30)) \
        ls += (double)e0 * e0 + (double)e1 * e1 + (double)e2 * e2 + (double)e3 * e3; \
    else if (lcol == 0) { int pos = atomicAdd(counter, 1); \
                          if (pos < cap) list[pos] = t; } }
#define EPIM(m) EPI1(m, 0) EPI1(m, 1) EPI1(m, 2) EPI1(m, 3)
    EPIM(0) EPIM(1) EPIM(2) EPIM(3)
#undef EPIM
#undef EPI1

    // block-level loss reduce -> ONE atomic per block
#pragma unroll
    for (int off = 32; off > 0; off >>= 1) ls += __shfl_down(ls, off, 64);
    if (lane == 0) wsum[tid >> 6] = ls;
    __syncthreads();
    if (tid == 0)
        atomicAdd(loss_acc, (wsum[0] + wsum[1]) + (wsum[2] + wsum[3]));
}

// ---- Phase 2: np-exact full re-scan of flagged tokens, one wave per token --
__global__ __launch_bounds__(256) void vq_rerank(
    const float* __restrict__ x, const float* __restrict__ cb,
    const float* __restrict__ cnorm, float* __restrict__ out,
    double* __restrict__ loss_acc, const int* __restrict__ counter,
    const int* __restrict__ list, int cap)
{
    int cnt = *counter; if (cnt > cap) cnt = cap;
    const int lane = threadIdx.x & 63;
    const int wid = (blockIdx.x << 2) + (threadIdx.x >> 6);
    const int nw = gridDim.x << 2;
    double ls = 0.0;

    for (int i = wid; i < cnt; i += nw) {
        const int t = list[i];
        float xr[DIM];
        {
            const float4* xv = (const float4*)(x + ((size_t)t << 6));
#pragma unroll
            for (int q = 0; q < 16; ++q) {
                float4 v = xv[q];
                xr[4 * q + 0] = v.x; xr[4 * q + 1] = v.y;
                xr[4 * q + 2] = v.z; xr[4 * q + 3] = v.w;
            }
        }
        const float x2 = np_sumsq64(xr);
        float best = __int_as_float(0x7f800000);
        int bi = 0;
#pragma unroll 2
        for (int j = 0; j < 8; ++j) {
            const int k = (j << 6) + lane;       // per-lane ascending k
            const float4* c = (const float4*)(cb + ((size_t)k << 6));
            float a = 0.f;
#pragma unroll
            for (int q = 0; q < 16; ++q) {       // float4 loads, chain d-asc
                float4 f = c[q];
                a = __fmaf_rn(xr[4 * q + 0], f.x, a);
                a = __fmaf_rn(xr[4 * q + 1], f.y, a);
                a = __fmaf_rn(xr[4 * q + 2], f.z, a);
                a = __fmaf_rn(xr[4 * q + 3], f.w, a);
            }
            float d2 = __fadd_rn(__fsub_rn(x2, __fmul_rn(2.0f, a)), cnorm[k]);
            bool p = d2 < best;
            best = p ? d2 : best; bi = p ? k : bi;
        }
#pragma unroll
        for (int off = 1; off < 64; off <<= 1) {
            float ob = __shfl_xor(best, off, 64);
            int   oi = __shfl_xor(bi, off, 64);
            bool take = (ob < best) || (ob == best && oi < bi);
            best = take ? ob : best; bi = take ? oi : bi;
        }
        float xv = x[((size_t)t << 6) + lane];
        float q  = cb[((size_t)bi << 6) + lane];
        float e = __fsub_rn(q, xv);
        out[((size_t)t << 6) + lane] = __fadd_rn(xv, e);
        ls += (double)e * (double)e;
    }
#pragma unroll
    for (int off = 32; off > 0; off >>= 1) ls += __shfl_down(ls, off, 64);
    if (lane == 0 && ls != 0.0) atomicAdd(loss_acc, ls);
}

__global__ void vq_final(const double* __restrict__ loss_acc,
                         float* __restrict__ out_loss)
{
    if (threadIdx.x == 0 && blockIdx.x == 0) {
        double mean = *loss_acc / (double)((size_t)N_TOK * DIM);
        *out_loss = (float)(1.25 * mean);
    }
}

extern "C" void kernel_launch(void* const* d_in, const int* in_sizes, int n_in,
                              void* d_out, int out_size, void* d_ws, size_t ws_size,
                              hipStream_t stream) {
    const float* x  = (const float*)d_in[0];
    const float* cb = (const float*)d_in[1];
    float* out = (float*)d_out;
    float* out_loss = out + (size_t)N_TOK * DIM;

    char* ws = (char*)d_ws;
    double* loss_acc = (double*)ws;                       // [0,8)
    int* counter = (int*)(ws + 8);                        // [8,12)
    float* cnorm = (float*)(ws + 64);                     // 2KB
    float* c2h = (float*)(ws + 2112);                     // 2KB
    unsigned short* cbh = (unsigned short*)(ws + 4608);   // 64KB
    unsigned short* cbl = (unsigned short*)(ws + 70144);  // 64KB
    int* list = (int*)(ws + 135680);                      // 120KB

    hipMemsetAsync(d_ws, 0, 16, stream);
    vq_prep<<<2, 256, 0, stream>>>(cb, cnorm, c2h, cbh, cbl);
    vq_screen<<<N_TOK / 256, 256, 0, stream>>>(x, cb, cbh, cbl, c2h, out,
                                               loss_acc, counter, list, LIST_CAP);
    vq_rerank<<<256, 256, 0, stream>>>(x, cb, cnorm, out, loss_acc,
                                       counter, list, LIST_CAP);
    vq_final<<<1, 64, 0, stream>>>(loss_acc, out_loss);
}